// Round 1
// baseline (607.742 us; speedup 1.0000x reference)
//
#include <hip/hip_runtime.h>
#include <hip/hip_bf16.h>

#define Bc 32
#define Nc 1024
#define Fc 32
#define Dc 64
#define Hc 64

// ---------------------------------------------------------------------------
// k_mu1: mu_1[b,n,d] = relu(sum_f xv[b,n,f]*mu1[f,d])
// grid (N/64, B), block 256
// ---------------------------------------------------------------------------
__global__ void k_mu1(const float* __restrict__ xv, const float* __restrict__ w,
                      float* __restrict__ mu_1) {
    const int nb = blockIdx.x, b = blockIdx.y, t = threadIdx.x;
    __shared__ float w_s[Fc * Dc];      // [f][d]
    __shared__ float x_s[64 * 33];      // [r][f], pad 33
    for (int i = t; i < Fc * Dc; i += 256) w_s[i] = w[i];
    const int n0 = nb * 64;
    for (int i = t; i < 64 * Fc; i += 256) {
        int r = i >> 5, f = i & 31;
        x_s[r * 33 + f] = xv[((size_t)b * Nc + n0 + r) * Fc + f];
    }
    __syncthreads();
    const int d = t & 63;
    const int rg = t >> 6;              // 0..3
    for (int ri = 0; ri < 16; ++ri) {
        int r = rg * 16 + ri;
        float acc = 0.f;
#pragma unroll
        for (int f = 0; f < Fc; ++f) acc = fmaf(x_s[r * 33 + f], w_s[f * Dc + d], acc);
        mu_1[((size_t)b * Nc + n0 + r) * Dc + d] = fmaxf(acc, 0.f);
    }
}

// ---------------------------------------------------------------------------
// k_c3: C3[n,d] = b2[d] + b3[d] + sum_e mu4[n,e]*W3[d,e]
//       mu4[n,e] = sum_m relu(adj[n,m]*W4[e] + b4[e])
// grid N, block 256
// ---------------------------------------------------------------------------
__global__ void k_c3(const float* __restrict__ adj, const float* __restrict__ W4,
                     const float* __restrict__ b4, const float* __restrict__ W3,
                     const float* __restrict__ b3, const float* __restrict__ b2,
                     float* __restrict__ C3) {
    const int n = blockIdx.x, t = threadIdx.x;
    const int e = t & 63, g = t >> 6;
    __shared__ float red[256];
    __shared__ float mu4_s[64];
    const float w4e = W4[e], b4e = b4[e];
    const float* arow = adj + (size_t)n * Nc;
    float acc = 0.f;
    for (int m = g * 256; m < g * 256 + 256; ++m)
        acc += fmaxf(fmaf(arow[m], w4e, b4e), 0.f);
    red[t] = acc;
    __syncthreads();
    if (g == 0) mu4_s[e] = red[e] + red[64 + e] + red[128 + e] + red[192 + e];
    __syncthreads();
    if (t < 64) {
        const int d = t;
        float a = b3[d] + b2[d];
        for (int ee = 0; ee < 64; ++ee) a = fmaf(mu4_s[ee], W3[d * 64 + ee], a);
        C3[n * 64 + d] = a;
    }
}

// ---------------------------------------------------------------------------
// k_round: mu_dst[b,n,:] = relu(mu_1[b,n,:] + (A[n,:] @ mu_src[b,:,:]) @ W2^T + C3[n,:])
// grid (N/64, B), block 256 (16x16 thread tile, 4x4 micro-tile)
// ---------------------------------------------------------------------------
#define TS 68   // main-loop LDS row stride (16B-aligned rows, low bank aliasing)
__global__ void k_round(const float* __restrict__ adj, const float* __restrict__ mu_src,
                        const float* __restrict__ mu_1, const float* __restrict__ C3,
                        const float* __restrict__ W2, float* __restrict__ mu_dst) {
    const int nb = blockIdx.x, b = blockIdx.y, t = threadIdx.x;
    const int tx = t & 15, ty = t >> 4;
    const int n0 = nb * 64;
    __shared__ float At[64 * TS];   // phase 1: A^T tile [m_local][n_local]; phase 2: pool (stride 65)
    __shared__ float Bs[64 * TS];   // phase 1: mu tile [m_local][d];        phase 2: W2 (stride 65)
    float acc[4][4] = {};

    for (int m0 = 0; m0 < Nc; m0 += 64) {
        for (int i = t; i < 4096; i += 256) {
            int r = i >> 6, c = i & 63;   // r: n-local, c: m-local
            float a = adj[(size_t)(n0 + r) * Nc + m0 + c];
            At[c * TS + r] = (a > 0.f) ? 1.f : 0.f;
        }
        for (int i = t; i < 4096; i += 256) {
            int r = i >> 6, c = i & 63;   // r: m-local, c: d
            Bs[r * TS + c] = mu_src[((size_t)b * Nc + m0 + r) * Dc + c];
        }
        __syncthreads();
#pragma unroll 8
        for (int k = 0; k < 64; ++k) {
            const float4 av = *(const float4*)&At[k * TS + ty * 4];
            const float4 bv = *(const float4*)&Bs[k * TS + tx * 4];
            acc[0][0] = fmaf(av.x, bv.x, acc[0][0]);
            acc[0][1] = fmaf(av.x, bv.y, acc[0][1]);
            acc[0][2] = fmaf(av.x, bv.z, acc[0][2]);
            acc[0][3] = fmaf(av.x, bv.w, acc[0][3]);
            acc[1][0] = fmaf(av.y, bv.x, acc[1][0]);
            acc[1][1] = fmaf(av.y, bv.y, acc[1][1]);
            acc[1][2] = fmaf(av.y, bv.z, acc[1][2]);
            acc[1][3] = fmaf(av.y, bv.w, acc[1][3]);
            acc[2][0] = fmaf(av.z, bv.x, acc[2][0]);
            acc[2][1] = fmaf(av.z, bv.y, acc[2][1]);
            acc[2][2] = fmaf(av.z, bv.z, acc[2][2]);
            acc[2][3] = fmaf(av.z, bv.w, acc[2][3]);
            acc[3][0] = fmaf(av.w, bv.x, acc[3][0]);
            acc[3][1] = fmaf(av.w, bv.y, acc[3][1]);
            acc[3][2] = fmaf(av.w, bv.z, acc[3][2]);
            acc[3][3] = fmaf(av.w, bv.w, acc[3][3]);
        }
        __syncthreads();
    }

    // phase 2: mu2 = pool @ W2^T (contract D=64), stride 65 to avoid conflicts
#pragma unroll
    for (int i = 0; i < 4; ++i)
#pragma unroll
        for (int j = 0; j < 4; ++j)
            At[(ty * 4 + i) * 65 + tx * 4 + j] = acc[i][j];
    for (int i = t; i < 4096; i += 256) {
        int r = i >> 6, c = i & 63;       // W2_s[d][e]
        Bs[r * 65 + c] = W2[r * 64 + c];
    }
    __syncthreads();
    float acc2[4][4] = {};
#pragma unroll 4
    for (int e = 0; e < 64; ++e) {
        float p[4], wv[4];
#pragma unroll
        for (int i = 0; i < 4; ++i) p[i] = At[(ty * 4 + i) * 65 + e];
#pragma unroll
        for (int j = 0; j < 4; ++j) wv[j] = Bs[(tx * 4 + j) * 65 + e];
#pragma unroll
        for (int i = 0; i < 4; ++i)
#pragma unroll
            for (int j = 0; j < 4; ++j) acc2[i][j] = fmaf(p[i], wv[j], acc2[i][j]);
    }
    // epilogue: relu(mu_1 + mu2 + C3), float4 stores
#pragma unroll
    for (int i = 0; i < 4; ++i) {
        const int n = n0 + ty * 4 + i;
        const size_t idx = ((size_t)b * Nc + n) * Dc + tx * 4;
        const float4 m1 = *(const float4*)&mu_1[idx];
        const float4 c3 = *(const float4*)&C3[n * 64 + tx * 4];
        float4 o;
        o.x = fmaxf(m1.x + acc2[i][0] + c3.x, 0.f);
        o.y = fmaxf(m1.y + acc2[i][1] + c3.y, 0.f);
        o.z = fmaxf(m1.z + acc2[i][2] + c3.z, 0.f);
        o.w = fmaxf(m1.w + acc2[i][3] + c3.w, 0.f);
        *(float4*)&mu_dst[idx] = o;
    }
}

// ---------------------------------------------------------------------------
// k_meanpost: meanpost[b,d] = relu(bq1[d] + sum_e mean_n(mu[b,n,e]) * Wq1[d,e])
//             c2base[b,h]  = breg[h] + sum_j (option[b]*Wq2[j]+bq2[j]) * Wreg[h,64+j]
// grid B, block 256
// ---------------------------------------------------------------------------
__global__ void k_meanpost(const float* __restrict__ mu, const float* __restrict__ Wq1,
                           const float* __restrict__ bq1, const float* __restrict__ option,
                           const float* __restrict__ Wq2, const float* __restrict__ bq2,
                           const float* __restrict__ Wreg, const float* __restrict__ breg,
                           float* __restrict__ meanpost, float* __restrict__ c2base) {
    const int b = blockIdx.x, t = threadIdx.x;
    const int e = t & 63, g = t >> 6;
    __shared__ float red[256];
    __shared__ float mean_s[64];
    __shared__ float q2_s[64];
    float acc = 0.f;
    for (int n = g * 256; n < g * 256 + 256; ++n)
        acc += mu[((size_t)b * Nc + n) * Dc + e];
    red[t] = acc;
    __syncthreads();
    if (g == 0) mean_s[e] = (red[e] + red[64 + e] + red[128 + e] + red[192 + e]) * (1.f / Nc);
    if (g == 1) q2_s[e] = fmaf(option[b], Wq2[e], bq2[e]);
    __syncthreads();
    if (t < 64) {
        const int d = t;
        float a = bq1[d];
        for (int ee = 0; ee < 64; ++ee) a = fmaf(mean_s[ee], Wq1[d * 64 + ee], a);
        meanpost[b * 64 + d] = fmaxf(a, 0.f);
    } else if (t < 128) {
        const int h = t - 64;
        float a = breg[h];
        for (int j = 0; j < 64; ++j) a = fmaf(q2_s[j], Wreg[h * 128 + 64 + j], a);
        c2base[b * 64 + h] = a;
    }
}

// ---------------------------------------------------------------------------
// k_final: out[b,r] = bq + sum_h relu(c2base[b,h] + sum_k src[k]*Wreg[h,k]) * Wq[h]
//          src = mu[b,r,:] for r<N, meanpost[b,:] for r==N
// grid (4, B), block 256 (one wave per row, lane = h)
// ---------------------------------------------------------------------------
__global__ void k_final(const float* __restrict__ mu, const float* __restrict__ meanpost,
                        const float* __restrict__ c2base, const float* __restrict__ Wreg,
                        const float* __restrict__ Wq, const float* __restrict__ bq,
                        float* __restrict__ out) {
    const int q = blockIdx.x, b = blockIdx.y, t = threadIdx.x;
    const int lane = t & 63, w = t >> 6;
    __shared__ float Wr[64 * 65];   // [h][k], k<64
    __shared__ float wq_s[64];
    for (int i = t; i < 4096; i += 256) {
        int h = i >> 6, k = i & 63;
        Wr[h * 65 + k] = Wreg[h * 128 + k];
    }
    if (t < 64) wq_s[t] = Wq[t];
    __syncthreads();
    const float bq0 = bq[0];
    const float base = c2base[b * 64 + lane];
    const int gw = q * 4 + w;       // 0..15
    for (int r = gw; r < Nc + 1; r += 16) {
        const float* src = (r < Nc) ? &mu[((size_t)b * Nc + r) * Dc] : &meanpost[b * 64];
        float acc = base;
#pragma unroll
        for (int k = 0; k < 64; ++k) acc = fmaf(src[k], Wr[lane * 65 + k], acc);
        float v = fmaxf(acc, 0.f) * wq_s[lane];
#pragma unroll
        for (int off = 32; off; off >>= 1) v += __shfl_down(v, off);
        if (lane == 0) out[(size_t)b * (Nc + 1) + r] = v + bq0;
    }
}

// ---------------------------------------------------------------------------
extern "C" void kernel_launch(void* const* d_in, const int* in_sizes, int n_in,
                              void* d_out, int out_size, void* d_ws, size_t ws_size,
                              hipStream_t stream) {
    const float* xv     = (const float*)d_in[0];
    const float* option = (const float*)d_in[1];
    const float* adj    = (const float*)d_in[2];
    const float* mu1w   = (const float*)d_in[3];
    const float* W2     = (const float*)d_in[4];
    const float* b2     = (const float*)d_in[5];
    const float* W3     = (const float*)d_in[6];
    const float* b3     = (const float*)d_in[7];
    const float* W4     = (const float*)d_in[8];
    const float* b4     = (const float*)d_in[9];
    const float* Wq1    = (const float*)d_in[10];
    const float* bq1    = (const float*)d_in[11];
    const float* Wq2    = (const float*)d_in[12];
    const float* bq2    = (const float*)d_in[13];
    const float* Wreg   = (const float*)d_in[14];
    const float* breg   = (const float*)d_in[15];
    const float* Wq     = (const float*)d_in[16];
    const float* bq     = (const float*)d_in[17];
    float* out = (float*)d_out;

    float* ws = (float*)d_ws;
    const size_t MU = (size_t)Bc * Nc * Dc;        // 2,097,152
    float* mu_1     = ws;
    float* bufA     = ws + MU;
    float* bufB     = ws + 2 * MU;
    float* C3       = ws + 3 * MU;                 // N*D
    float* meanpost = C3 + (size_t)Nc * Dc;        // B*D
    float* c2base   = meanpost + (size_t)Bc * Dc;  // B*H

    k_mu1<<<dim3(Nc / 64, Bc), 256, 0, stream>>>(xv, mu1w, mu_1);
    k_c3<<<Nc, 256, 0, stream>>>(adj, W4, b4, W3, b3, b2, C3);
    // T-1 = 3 rounds, ping-pong: mu_1 -> bufA -> bufB -> bufA
    k_round<<<dim3(Nc / 64, Bc), 256, 0, stream>>>(adj, mu_1, mu_1, C3, W2, bufA);
    k_round<<<dim3(Nc / 64, Bc), 256, 0, stream>>>(adj, bufA, mu_1, C3, W2, bufB);
    k_round<<<dim3(Nc / 64, Bc), 256, 0, stream>>>(adj, bufB, mu_1, C3, W2, bufA);
    k_meanpost<<<Bc, 256, 0, stream>>>(bufA, Wq1, bq1, option, Wq2, bq2, Wreg, breg,
                                       meanpost, c2base);
    k_final<<<dim3(4, Bc), 256, 0, stream>>>(bufA, meanpost, c2base, Wreg, Wq, bq, out);
}

// Round 2
// 249.850 us; speedup vs baseline: 2.4324x; 2.4324x over previous
//
#include <hip/hip_runtime.h>
#include <hip/hip_bf16.h>

#define Bc 32
#define Nc 1024
#define Fc 32
#define Dc 64
#define Hc 64

typedef __bf16 bf16;
typedef __bf16 bf16x4 __attribute__((ext_vector_type(4)));
typedef __bf16 bf16x8 __attribute__((ext_vector_type(8)));
typedef float  f32x4  __attribute__((ext_vector_type(4)));

#define AS_STRIDE 136   // bf16 elements; 272B rows (16B-aligned), uniform bank spread
#define MS_STRIDE 72    // bf16 elements; 144B rows (16B-aligned)

// ---------------------------------------------------------------------------
// k_prep: Abf[n][m] = (adj[n][m] > 0) as bf16 {0,1};  W2bf[d][e] = bf16(W2[d][e])
// grid 1025, block 256
// ---------------------------------------------------------------------------
__global__ void k_prep(const float* __restrict__ adj, const float* __restrict__ W2,
                       bf16* __restrict__ Abf, bf16* __restrict__ W2bf) {
    const int t = threadIdx.x;
    if (blockIdx.x < 1024) {
        const int i = blockIdx.x * 1024 + t * 4;
        const float4 a = *(const float4*)&adj[i];
        bf16x4 o;
        o[0] = (bf16)((a.x > 0.f) ? 1.f : 0.f);
        o[1] = (bf16)((a.y > 0.f) ? 1.f : 0.f);
        o[2] = (bf16)((a.z > 0.f) ? 1.f : 0.f);
        o[3] = (bf16)((a.w > 0.f) ? 1.f : 0.f);
        *(bf16x4*)&Abf[i] = o;
    } else {
        for (int j = t * 16; j < t * 16 + 16; ++j) W2bf[j] = (bf16)W2[j];
    }
}

// ---------------------------------------------------------------------------
// k_c3: C3[n,d] = b2[d] + b3[d] + sum_e mu4[n,e]*W3[d,e]
// grid N, block 256 (unchanged from R1 — correct & cheap)
// ---------------------------------------------------------------------------
__global__ void k_c3(const float* __restrict__ adj, const float* __restrict__ W4,
                     const float* __restrict__ b4, const float* __restrict__ W3,
                     const float* __restrict__ b3, const float* __restrict__ b2,
                     float* __restrict__ C3) {
    const int n = blockIdx.x, t = threadIdx.x;
    const int e = t & 63, g = t >> 6;
    __shared__ float red[256];
    __shared__ float mu4_s[64];
    const float w4e = W4[e], b4e = b4[e];
    const float* arow = adj + (size_t)n * Nc;
    float acc = 0.f;
    for (int m = g * 256; m < g * 256 + 256; ++m)
        acc += fmaxf(fmaf(arow[m], w4e, b4e), 0.f);
    red[t] = acc;
    __syncthreads();
    if (g == 0) mu4_s[e] = red[e] + red[64 + e] + red[128 + e] + red[192 + e];
    __syncthreads();
    if (t < 64) {
        const int d = t;
        float a = b3[d] + b2[d];
        for (int ee = 0; ee < 64; ++ee) a = fmaf(mu4_s[ee], W3[d * 64 + ee], a);
        C3[n * 64 + d] = a;
    }
}

// ---------------------------------------------------------------------------
// k_mu1: mu_1 = relu(xv@mu1) (fp32 out) AND X0 = mu_1 @ W2^T as bf16 [b][d][n]
// grid (N/64, B), block 256
// ---------------------------------------------------------------------------
__global__ void k_mu1(const float* __restrict__ xv, const float* __restrict__ w,
                      const bf16* __restrict__ W2bf,
                      float* __restrict__ mu_1, bf16* __restrict__ Xt) {
    const int nb = blockIdx.x, b = blockIdx.y, t = threadIdx.x;
    const int n0 = nb * 64;
    __shared__ float w_s[Fc * Dc];
    __shared__ float x_s[64 * 33];
    __shared__ bf16  muS[64 * MS_STRIDE];
    __shared__ bf16  W2s[64 * MS_STRIDE];
    for (int i = t; i < Fc * Dc; i += 256) w_s[i] = w[i];
    for (int i = t; i < 64 * Fc; i += 256) {
        int r = i >> 5, f = i & 31;
        x_s[r * 33 + f] = xv[((size_t)b * Nc + n0 + r) * Fc + f];
    }
    // stage W2s[d][e] (B-operand for phase 2): 512 16B chunks
#pragma unroll
    for (int i = 0; i < 2; ++i) {
        int g = i * 256 + t, row = g >> 3, c = g & 7;
        *(bf16x8*)&W2s[row * MS_STRIDE + c * 8] = *(const bf16x8*)&W2bf[row * 64 + c * 8];
    }
    __syncthreads();
    const int d = t & 63, rg = t >> 6;
    for (int ri = 0; ri < 16; ++ri) {
        int r = rg * 16 + ri;
        float acc = 0.f;
#pragma unroll
        for (int f = 0; f < Fc; ++f) acc = fmaf(x_s[r * 33 + f], w_s[f * Dc + d], acc);
        acc = fmaxf(acc, 0.f);
        mu_1[((size_t)b * Nc + n0 + r) * Dc + d] = acc;
        muS[r * MS_STRIDE + d] = (bf16)acc;
    }
    __syncthreads();
    // phase 2: X0 = mu_1 @ W2^T via MFMA. wave w: rows 16w..16w+15, all 64 cols
    const int l = t & 63, wv = t >> 6, lm = l & 15, q = l >> 4;
    f32x4 xacc[4];
#pragma unroll
    for (int ct = 0; ct < 4; ++ct)
#pragma unroll
        for (int r = 0; r < 4; ++r) xacc[ct][r] = 0.f;
#pragma unroll
    for (int s = 0; s < 2; ++s) {
        bf16x8 a = *(const bf16x8*)&muS[(wv * 16 + lm) * MS_STRIDE + s * 32 + q * 8];
#pragma unroll
        for (int ct = 0; ct < 4; ++ct) {
            bf16x8 bv = *(const bf16x8*)&W2s[(ct * 16 + lm) * MS_STRIDE + s * 32 + q * 8];
            xacc[ct] = __builtin_amdgcn_mfma_f32_16x16x32_bf16(a, bv, xacc[ct], 0, 0, 0);
        }
    }
#pragma unroll
    for (int ct = 0; ct < 4; ++ct) {
        const int dd = ct * 16 + lm;
        bf16x4 p;
#pragma unroll
        for (int r = 0; r < 4; ++r) p[r] = (bf16)xacc[ct][r];
        *(bf16x4*)&Xt[(size_t)b * 65536 + (size_t)dd * 1024 + n0 + wv * 16 + q * 4] = p;
    }
}

// ---------------------------------------------------------------------------
// k_round: P = A_tile @ X (MFMA, K=1024), mu = relu(mu_1 + P + C3),
//          then (non-final) X_out = mu @ W2^T (MFMA) as bf16 [b][d][n],
//          or (final) store mu fp32.
// grid (N/64, B), block 256 = 4 waves; wave w: rows 16w..16w+15, cols 0..63
// ---------------------------------------------------------------------------
template <bool FINAL>
__global__ void k_round(const bf16* __restrict__ Abf, const bf16* __restrict__ Xt_in,
                        const float* __restrict__ mu_1, const float* __restrict__ C3,
                        const bf16* __restrict__ W2bf, bf16* __restrict__ Xt_out,
                        float* __restrict__ mu_fin) {
    const int nb = blockIdx.x, b = blockIdx.y, t = threadIdx.x;
    const int n0 = nb * 64;
    const int l = t & 63, wv = t >> 6, lm = l & 15, q = l >> 4;
    __shared__ bf16 As[64 * AS_STRIDE];
    __shared__ bf16 Xs[64 * AS_STRIDE];
    __shared__ bf16 muS[64 * MS_STRIDE];
    __shared__ bf16 W2s[64 * MS_STRIDE];

    if (!FINAL) {
#pragma unroll
        for (int i = 0; i < 2; ++i) {
            int g = i * 256 + t, row = g >> 3, c = g & 7;
            *(bf16x8*)&W2s[row * MS_STRIDE + c * 8] = *(const bf16x8*)&W2bf[row * 64 + c * 8];
        }
    }

    f32x4 acc[4];
#pragma unroll
    for (int ct = 0; ct < 4; ++ct)
#pragma unroll
        for (int r = 0; r < 4; ++r) acc[ct][r] = 0.f;

    const bf16* Arow = Abf + (size_t)n0 * 1024;
    const bf16* Xrow = Xt_in + (size_t)b * 65536;
    for (int kc = 0; kc < 1024; kc += 128) {
        // stage 64x128 bf16 tiles (1024 16B chunks each): coalesced 16B/lane
#pragma unroll
        for (int i = 0; i < 4; ++i) {
            int g = i * 256 + t, row = g >> 4, c = g & 15;
            *(bf16x8*)&As[row * AS_STRIDE + c * 8] =
                *(const bf16x8*)&Arow[(size_t)row * 1024 + kc + c * 8];
            *(bf16x8*)&Xs[row * AS_STRIDE + c * 8] =
                *(const bf16x8*)&Xrow[(size_t)row * 1024 + kc + c * 8];
        }
        __syncthreads();
#pragma unroll
        for (int s = 0; s < 4; ++s) {
            bf16x8 a = *(const bf16x8*)&As[(wv * 16 + lm) * AS_STRIDE + s * 32 + q * 8];
#pragma unroll
            for (int ct = 0; ct < 4; ++ct) {
                bf16x8 bv = *(const bf16x8*)&Xs[(ct * 16 + lm) * AS_STRIDE + s * 32 + q * 8];
                acc[ct] = __builtin_amdgcn_mfma_f32_16x16x32_bf16(a, bv, acc[ct], 0, 0, 0);
            }
        }
        __syncthreads();
    }

    // epilogue: mu = relu(mu_1 + P + C3).  C/D: col = lane&15 (+16*ct), row = q*4+r (+16w)
    float vals[4][4];
#pragma unroll
    for (int ct = 0; ct < 4; ++ct) {
        const int col = ct * 16 + lm;
#pragma unroll
        for (int r = 0; r < 4; ++r) {
            const int n = n0 + wv * 16 + q * 4 + r;
            float v = mu_1[((size_t)b * Nc + n) * Dc + col] + acc[ct][r] + C3[n * 64 + col];
            vals[ct][r] = fmaxf(v, 0.f);
        }
    }

    if (FINAL) {
#pragma unroll
        for (int ct = 0; ct < 4; ++ct) {
            const int col = ct * 16 + lm;
#pragma unroll
            for (int r = 0; r < 4; ++r) {
                const int n = n0 + wv * 16 + q * 4 + r;
                mu_fin[((size_t)b * Nc + n) * Dc + col] = vals[ct][r];
            }
        }
    } else {
        // write mu tile to LDS as bf16 in [n][e] layout for A-fragment reads
#pragma unroll
        for (int ct = 0; ct < 4; ++ct) {
            const int col = ct * 16 + lm;
#pragma unroll
            for (int r = 0; r < 4; ++r)
                muS[(wv * 16 + q * 4 + r) * MS_STRIDE + col] = (bf16)vals[ct][r];
        }
        __syncthreads();
        f32x4 xacc[4];
#pragma unroll
        for (int ct = 0; ct < 4; ++ct)
#pragma unroll
            for (int r = 0; r < 4; ++r) xacc[ct][r] = 0.f;
#pragma unroll
        for (int s = 0; s < 2; ++s) {
            bf16x8 a = *(const bf16x8*)&muS[(wv * 16 + lm) * MS_STRIDE + s * 32 + q * 8];
#pragma unroll
            for (int ct = 0; ct < 4; ++ct) {
                bf16x8 bv = *(const bf16x8*)&W2s[(ct * 16 + lm) * MS_STRIDE + s * 32 + q * 8];
                xacc[ct] = __builtin_amdgcn_mfma_f32_16x16x32_bf16(a, bv, xacc[ct], 0, 0, 0);
            }
        }
#pragma unroll
        for (int ct = 0; ct < 4; ++ct) {
            const int dd = ct * 16 + lm;
            bf16x4 p;
#pragma unroll
            for (int r = 0; r < 4; ++r) p[r] = (bf16)xacc[ct][r];
            *(bf16x4*)&Xt_out[(size_t)b * 65536 + (size_t)dd * 1024 + n0 + wv * 16 + q * 4] = p;
        }
    }
}

// ---------------------------------------------------------------------------
// k_meanpost (unchanged)
// ---------------------------------------------------------------------------
__global__ void k_meanpost(const float* __restrict__ mu, const float* __restrict__ Wq1,
                           const float* __restrict__ bq1, const float* __restrict__ option,
                           const float* __restrict__ Wq2, const float* __restrict__ bq2,
                           const float* __restrict__ Wreg, const float* __restrict__ breg,
                           float* __restrict__ meanpost, float* __restrict__ c2base) {
    const int b = blockIdx.x, t = threadIdx.x;
    const int e = t & 63, g = t >> 6;
    __shared__ float red[256];
    __shared__ float mean_s[64];
    __shared__ float q2_s[64];
    float acc = 0.f;
    for (int n = g * 256; n < g * 256 + 256; ++n)
        acc += mu[((size_t)b * Nc + n) * Dc + e];
    red[t] = acc;
    __syncthreads();
    if (g == 0) mean_s[e] = (red[e] + red[64 + e] + red[128 + e] + red[192 + e]) * (1.f / Nc);
    if (g == 1) q2_s[e] = fmaf(option[b], Wq2[e], bq2[e]);
    __syncthreads();
    if (t < 64) {
        const int d = t;
        float a = bq1[d];
        for (int ee = 0; ee < 64; ++ee) a = fmaf(mean_s[ee], Wq1[d * 64 + ee], a);
        meanpost[b * 64 + d] = fmaxf(a, 0.f);
    } else if (t < 128) {
        const int h = t - 64;
        float a = breg[h];
        for (int j = 0; j < 64; ++j) a = fmaf(q2_s[j], Wreg[h * 128 + 64 + j], a);
        c2base[b * 64 + h] = a;
    }
}

// ---------------------------------------------------------------------------
// k_final (unchanged)
// ---------------------------------------------------------------------------
__global__ void k_final(const float* __restrict__ mu, const float* __restrict__ meanpost,
                        const float* __restrict__ c2base, const float* __restrict__ Wreg,
                        const float* __restrict__ Wq, const float* __restrict__ bq,
                        float* __restrict__ out) {
    const int qb = blockIdx.x, b = blockIdx.y, t = threadIdx.x;
    const int lane = t & 63, w = t >> 6;
    __shared__ float Wr[64 * 65];
    __shared__ float wq_s[64];
    for (int i = t; i < 4096; i += 256) {
        int h = i >> 6, k = i & 63;
        Wr[h * 65 + k] = Wreg[h * 128 + k];
    }
    if (t < 64) wq_s[t] = Wq[t];
    __syncthreads();
    const float bq0 = bq[0];
    const float base = c2base[b * 64 + lane];
    const int gw = qb * 4 + w;
    for (int r = gw; r < Nc + 1; r += 16) {
        const float* src = (r < Nc) ? &mu[((size_t)b * Nc + r) * Dc] : &meanpost[b * 64];
        float acc = base;
#pragma unroll
        for (int k = 0; k < 64; ++k) acc = fmaf(src[k], Wr[lane * 65 + k], acc);
        float v = fmaxf(acc, 0.f) * wq_s[lane];
#pragma unroll
        for (int off = 32; off; off >>= 1) v += __shfl_down(v, off);
        if (lane == 0) out[(size_t)b * (Nc + 1) + r] = v + bq0;
    }
}

// ---------------------------------------------------------------------------
extern "C" void kernel_launch(void* const* d_in, const int* in_sizes, int n_in,
                              void* d_out, int out_size, void* d_ws, size_t ws_size,
                              hipStream_t stream) {
    const float* xv     = (const float*)d_in[0];
    const float* option = (const float*)d_in[1];
    const float* adj    = (const float*)d_in[2];
    const float* mu1w   = (const float*)d_in[3];
    const float* W2     = (const float*)d_in[4];
    const float* b2     = (const float*)d_in[5];
    const float* W3     = (const float*)d_in[6];
    const float* b3     = (const float*)d_in[7];
    const float* W4     = (const float*)d_in[8];
    const float* b4     = (const float*)d_in[9];
    const float* Wq1    = (const float*)d_in[10];
    const float* bq1    = (const float*)d_in[11];
    const float* Wq2    = (const float*)d_in[12];
    const float* bq2    = (const float*)d_in[13];
    const float* Wreg   = (const float*)d_in[14];
    const float* breg   = (const float*)d_in[15];
    const float* Wq     = (const float*)d_in[16];
    const float* bq     = (const float*)d_in[17];
    float* out = (float*)d_out;

    float* ws = (float*)d_ws;
    const size_t MU = (size_t)Bc * Nc * Dc;          // 2,097,152
    float* mu_1     = ws;
    float* mu_fin   = ws + MU;
    float* C3       = ws + 2 * MU;                   // N*D = 65536
    float* meanpost = C3 + 65536;                    // 2048
    float* c2base   = meanpost + 2048;               // 2048
    bf16*  Abf      = (bf16*)(c2base + 2048);        // 1M bf16
    bf16*  W2bf     = Abf + (size_t)Nc * Nc;         // 4096 bf16
    bf16*  Xt0      = W2bf + 4096;                   // B*D*N bf16
    bf16*  Xt1      = Xt0 + MU;

    k_prep<<<1025, 256, 0, stream>>>(adj, W2, Abf, W2bf);
    k_c3<<<Nc, 256, 0, stream>>>(adj, W4, b4, W3, b3, b2, C3);
    k_mu1<<<dim3(Nc / 64, Bc), 256, 0, stream>>>(xv, mu1w, W2bf, mu_1, Xt0);
    k_round<false><<<dim3(Nc / 64, Bc), 256, 0, stream>>>(Abf, Xt0, mu_1, C3, W2bf, Xt1, nullptr);
    k_round<false><<<dim3(Nc / 64, Bc), 256, 0, stream>>>(Abf, Xt1, mu_1, C3, W2bf, Xt0, nullptr);
    k_round<true><<<dim3(Nc / 64, Bc), 256, 0, stream>>>(Abf, Xt0, mu_1, C3, W2bf, nullptr, mu_fin);
    k_meanpost<<<Bc, 256, 0, stream>>>(mu_fin, Wq1, bq1, option, Wq2, bq2, Wreg, breg,
                                       meanpost, c2base);
    k_final<<<dim3(4, Bc), 256, 0, stream>>>(mu_fin, meanpost, c2base, Wreg, Wq, bq, out);
}

// Round 4
// 178.991 us; speedup vs baseline: 3.3954x; 1.3959x over previous
//
#include <hip/hip_runtime.h>
#include <hip/hip_bf16.h>

#define Bc 32
#define Nc 1024
#define Fc 32
#define Dc 64
#define Hc 64

typedef __bf16 bf16;
typedef __bf16 bf16x4 __attribute__((ext_vector_type(4)));
typedef __bf16 bf16x8 __attribute__((ext_vector_type(8)));
typedef float  f32x4  __attribute__((ext_vector_type(4)));

#define AS_STRIDE 136   // bf16 elements; 272B rows (16B-aligned), uniform bank spread
#define MS_STRIDE 72    // bf16 elements; 144B rows (16B-aligned)
#define LDS_MAIN  (2 * 64 * AS_STRIDE * 2)                 // As + Xs       = 34816 B
#define LDS_NONF  (LDS_MAIN + 2 * 64 * MS_STRIDE * 2)      // + muHi + WHi  = 53248 B
#define LDS_FIN   (LDS_NONF + 2 * 64 * MS_STRIDE * 2)      // + muLo + WLo  = 71680 B

// ---------------------------------------------------------------------------
// k_prep: Abf[n][m] = (adj[n][m] > 0) as bf16 {0,1};  W2bf = bf16(W2);
//         block 1025: c2base[b,h] = breg[h] + sum_j (option[b]*Wq2[j]+bq2[j])*Wreg[h,64+j]
//                     and zero musum
// grid 1026, block 256
// ---------------------------------------------------------------------------
__global__ void k_prep(const float* __restrict__ adj, const float* __restrict__ W2,
                       const float* __restrict__ option, const float* __restrict__ Wq2,
                       const float* __restrict__ bq2, const float* __restrict__ Wreg,
                       const float* __restrict__ breg,
                       bf16* __restrict__ Abf, bf16* __restrict__ W2bf,
                       float* __restrict__ c2base, float* __restrict__ musum) {
    const int t = threadIdx.x;
    if (blockIdx.x < 1024) {
        const int i = blockIdx.x * 1024 + t * 4;
        const float4 a = *(const float4*)&adj[i];
        bf16x4 o;
        o[0] = (bf16)((a.x > 0.f) ? 1.f : 0.f);
        o[1] = (bf16)((a.y > 0.f) ? 1.f : 0.f);
        o[2] = (bf16)((a.z > 0.f) ? 1.f : 0.f);
        o[3] = (bf16)((a.w > 0.f) ? 1.f : 0.f);
        *(bf16x4*)&Abf[i] = o;
    } else if (blockIdx.x == 1024) {
        for (int j = t * 16; j < t * 16 + 16; ++j) W2bf[j] = (bf16)W2[j];
    } else {
        for (int i = t; i < 2048; i += 256) musum[i] = 0.f;
        for (int i = t; i < 2048; i += 256) {
            const int b = i >> 6, h = i & 63;
            const float opt = option[b];
            float a = breg[h];
#pragma unroll
            for (int j = 0; j < 64; ++j)
                a = fmaf(fmaf(opt, Wq2[j], bq2[j]), Wreg[h * 128 + 64 + j], a);
            c2base[i] = a;
        }
    }
}

// ---------------------------------------------------------------------------
// k_c3: C3[n,d] = b2[d] + b3[d] + sum_e mu4[n,e]*W3[d,e]
// grid N, block 256
// ---------------------------------------------------------------------------
__global__ void k_c3(const float* __restrict__ adj, const float* __restrict__ W4,
                     const float* __restrict__ b4, const float* __restrict__ W3,
                     const float* __restrict__ b3, const float* __restrict__ b2,
                     float* __restrict__ C3) {
    const int n = blockIdx.x, t = threadIdx.x;
    const int e = t & 63, g = t >> 6;
    __shared__ float red[256];
    __shared__ float mu4_s[64];
    const float w4e = W4[e], b4e = b4[e];
    const float* arow = adj + (size_t)n * Nc;
    float acc = 0.f;
    for (int m = g * 256; m < g * 256 + 256; ++m)
        acc += fmaxf(fmaf(arow[m], w4e, b4e), 0.f);
    red[t] = acc;
    __syncthreads();
    if (g == 0) mu4_s[e] = red[e] + red[64 + e] + red[128 + e] + red[192 + e];
    __syncthreads();
    if (t < 64) {
        const int d = t;
        float a = b3[d] + b2[d];
        for (int ee = 0; ee < 64; ++ee) a = fmaf(mu4_s[ee], W3[d * 64 + ee], a);
        C3[n * 64 + d] = a;
    }
}

// ---------------------------------------------------------------------------
// k_mu1: mu_1 = relu(xv@mu1) (fp32 out) AND X0 = mu_1 @ W2^T as bf16 [b][d][n]
// grid (N/64, B), block 256
// ---------------------------------------------------------------------------
__global__ void k_mu1(const float* __restrict__ xv, const float* __restrict__ w,
                      const bf16* __restrict__ W2bf,
                      float* __restrict__ mu_1, bf16* __restrict__ Xt) {
    const int nb = blockIdx.x, b = blockIdx.y, t = threadIdx.x;
    const int n0 = nb * 64;
    __shared__ float w_s[Fc * Dc];
    __shared__ float x_s[64 * 33];
    __shared__ bf16  muS[64 * MS_STRIDE];
    __shared__ bf16  W2s[64 * MS_STRIDE];
    for (int i = t; i < Fc * Dc; i += 256) w_s[i] = w[i];
    for (int i = t; i < 64 * Fc; i += 256) {
        int r = i >> 5, f = i & 31;
        x_s[r * 33 + f] = xv[((size_t)b * Nc + n0 + r) * Fc + f];
    }
#pragma unroll
    for (int i = 0; i < 2; ++i) {
        int g = i * 256 + t, row = g >> 3, c = g & 7;
        *(bf16x8*)&W2s[row * MS_STRIDE + c * 8] = *(const bf16x8*)&W2bf[row * 64 + c * 8];
    }
    __syncthreads();
    const int d = t & 63, rg = t >> 6;
    for (int ri = 0; ri < 16; ++ri) {
        int r = rg * 16 + ri;
        float acc = 0.f;
#pragma unroll
        for (int f = 0; f < Fc; ++f) acc = fmaf(x_s[r * 33 + f], w_s[f * Dc + d], acc);
        acc = fmaxf(acc, 0.f);
        mu_1[((size_t)b * Nc + n0 + r) * Dc + d] = acc;
        muS[r * MS_STRIDE + d] = (bf16)acc;
    }
    __syncthreads();
    const int l = t & 63, wv = t >> 6, lm = l & 15, q = l >> 4;
    f32x4 xacc[4];
#pragma unroll
    for (int ct = 0; ct < 4; ++ct)
#pragma unroll
        for (int r = 0; r < 4; ++r) xacc[ct][r] = 0.f;
#pragma unroll
    for (int s = 0; s < 2; ++s) {
        bf16x8 a = *(const bf16x8*)&muS[(wv * 16 + lm) * MS_STRIDE + s * 32 + q * 8];
#pragma unroll
        for (int ct = 0; ct < 4; ++ct) {
            bf16x8 bv = *(const bf16x8*)&W2s[(ct * 16 + lm) * MS_STRIDE + s * 32 + q * 8];
            xacc[ct] = __builtin_amdgcn_mfma_f32_16x16x32_bf16(a, bv, xacc[ct], 0, 0, 0);
        }
    }
#pragma unroll
    for (int ct = 0; ct < 4; ++ct) {
        const int dd = ct * 16 + lm;
        bf16x4 p;
#pragma unroll
        for (int r = 0; r < 4; ++r) p[r] = (bf16)xacc[ct][r];
        *(bf16x4*)&Xt[(size_t)b * 65536 + (size_t)dd * 1024 + n0 + wv * 16 + q * 4] = p;
    }
}

// ---------------------------------------------------------------------------
// k_round: P = A_tile @ X (MFMA, K=1024), mu = relu(mu_1 + P + C3), then:
//   non-final: X_out = mu @ W2^T (MFMA) as bf16 [b][d][n]
//   final:     out[b,n] = bq + sum_h relu((mu @ Wreg[:,:64]^T)[n,h] + c2base[b,h])*Wq[h]
//              via SPLIT-PRECISION bf16 MFMA (mu,Wreg as hi+lo; 3 of 4 cross products)
//              plus musum[b,d] += sum_n mu[b,n,d] (atomic, fp32, for the mean row)
// grid (N/64, B), block 256 = 4 waves; dynamic LDS: LDS_NONF / LDS_FIN bytes
// ---------------------------------------------------------------------------
template <bool FINAL>
__global__ void k_round(const bf16* __restrict__ Abf, const bf16* __restrict__ Xt_in,
                        const float* __restrict__ mu_1, const float* __restrict__ C3,
                        const bf16* __restrict__ W2bf, bf16* __restrict__ Xt_out,
                        const float* __restrict__ Wreg, const float* __restrict__ c2base,
                        const float* __restrict__ Wq, const float* __restrict__ bq,
                        float* __restrict__ musum, float* __restrict__ out) {
    const int nb = blockIdx.x, b = blockIdx.y, t = threadIdx.x;
    const int n0 = nb * 64;
    const int l = t & 63, wv = t >> 6, lm = l & 15, q = l >> 4;
    extern __shared__ char smem[];
    bf16* As   = (bf16*)smem;                 // 64*AS_STRIDE
    bf16* Xs   = As + 64 * AS_STRIDE;         // 64*AS_STRIDE
    bf16* muHi = Xs + 64 * AS_STRIDE;         // 64*MS_STRIDE
    bf16* WHi  = muHi + 64 * MS_STRIDE;       // 64*MS_STRIDE (non-final: W2bf)
    bf16* muLo = WHi + 64 * MS_STRIDE;        // FINAL only
    bf16* WLo  = muLo + 64 * MS_STRIDE;       // FINAL only

    if (!FINAL) {
#pragma unroll
        for (int i = 0; i < 2; ++i) {
            int g = i * 256 + t, row = g >> 3, c = g & 7;
            *(bf16x8*)&WHi[row * MS_STRIDE + c * 8] = *(const bf16x8*)&W2bf[row * 64 + c * 8];
        }
    } else {
        // stage Wreg[h][d<64] as hi/lo bf16
#pragma unroll
        for (int i = 0; i < 4; ++i) {
            int g = i * 1024 + t * 4;
            int h = g >> 6, d = g & 63;
            const float4 w4 = *(const float4*)&Wreg[h * 128 + d];
            bf16x4 ohi, olo;
            ohi[0] = (bf16)w4.x; olo[0] = (bf16)(w4.x - (float)ohi[0]);
            ohi[1] = (bf16)w4.y; olo[1] = (bf16)(w4.y - (float)ohi[1]);
            ohi[2] = (bf16)w4.z; olo[2] = (bf16)(w4.z - (float)ohi[2]);
            ohi[3] = (bf16)w4.w; olo[3] = (bf16)(w4.w - (float)ohi[3]);
            *(bf16x4*)&WHi[h * MS_STRIDE + d] = ohi;
            *(bf16x4*)&WLo[h * MS_STRIDE + d] = olo;
        }
    }

    f32x4 acc[4];
#pragma unroll
    for (int ct = 0; ct < 4; ++ct)
#pragma unroll
        for (int r = 0; r < 4; ++r) acc[ct][r] = 0.f;

    const bf16* Arow = Abf + (size_t)n0 * 1024;
    const bf16* Xrow = Xt_in + (size_t)b * 65536;
    for (int kc = 0; kc < 1024; kc += 128) {
#pragma unroll
        for (int i = 0; i < 4; ++i) {
            int g = i * 256 + t, row = g >> 4, c = g & 15;
            *(bf16x8*)&As[row * AS_STRIDE + c * 8] =
                *(const bf16x8*)&Arow[(size_t)row * 1024 + kc + c * 8];
            *(bf16x8*)&Xs[row * AS_STRIDE + c * 8] =
                *(const bf16x8*)&Xrow[(size_t)row * 1024 + kc + c * 8];
        }
        __syncthreads();
#pragma unroll
        for (int s = 0; s < 4; ++s) {
            bf16x8 a = *(const bf16x8*)&As[(wv * 16 + lm) * AS_STRIDE + s * 32 + q * 8];
#pragma unroll
            for (int ct = 0; ct < 4; ++ct) {
                bf16x8 bv = *(const bf16x8*)&Xs[(ct * 16 + lm) * AS_STRIDE + s * 32 + q * 8];
                acc[ct] = __builtin_amdgcn_mfma_f32_16x16x32_bf16(a, bv, acc[ct], 0, 0, 0);
            }
        }
        __syncthreads();
    }

    // epilogue: mu = relu(mu_1 + P + C3).  C/D: col = lane&15 (+16*ct), row = q*4+r (+16w)
    float vals[4][4];
#pragma unroll
    for (int ct = 0; ct < 4; ++ct) {
        const int col = ct * 16 + lm;
#pragma unroll
        for (int r = 0; r < 4; ++r) {
            const int n = n0 + wv * 16 + q * 4 + r;
            float v = mu_1[((size_t)b * Nc + n) * Dc + col] + acc[ct][r] + C3[n * 64 + col];
            vals[ct][r] = fmaxf(v, 0.f);
        }
    }

    // write mu tile to LDS as bf16 [n][d] (FINAL: hi/lo split)
#pragma unroll
    for (int ct = 0; ct < 4; ++ct) {
        const int col = ct * 16 + lm;
#pragma unroll
        for (int r = 0; r < 4; ++r) {
            const int row = wv * 16 + q * 4 + r;
            const float v = vals[ct][r];
            const bf16 hi = (bf16)v;
            muHi[row * MS_STRIDE + col] = hi;
            if (FINAL) muLo[row * MS_STRIDE + col] = (bf16)(v - (float)hi);
        }
    }

    if (FINAL) {
        // musum[b,d] += sum over this wave's 16 rows (fp32 values)
#pragma unroll
        for (int ct = 0; ct < 4; ++ct) {
            float s = vals[ct][0] + vals[ct][1] + vals[ct][2] + vals[ct][3];
            s += __shfl_xor(s, 16);
            s += __shfl_xor(s, 32);
            if (q == 0) atomicAdd(&musum[b * 64 + ct * 16 + lm], s);
        }
    }

    __syncthreads();
    f32x4 xacc[4];
#pragma unroll
    for (int ct = 0; ct < 4; ++ct)
#pragma unroll
        for (int r = 0; r < 4; ++r) xacc[ct][r] = 0.f;

    if (!FINAL) {
#pragma unroll
        for (int s = 0; s < 2; ++s) {
            bf16x8 a = *(const bf16x8*)&muHi[(wv * 16 + lm) * MS_STRIDE + s * 32 + q * 8];
#pragma unroll
            for (int ct = 0; ct < 4; ++ct) {
                bf16x8 bv = *(const bf16x8*)&WHi[(ct * 16 + lm) * MS_STRIDE + s * 32 + q * 8];
                xacc[ct] = __builtin_amdgcn_mfma_f32_16x16x32_bf16(a, bv, xacc[ct], 0, 0, 0);
            }
        }
#pragma unroll
        for (int ct = 0; ct < 4; ++ct) {
            const int dd = ct * 16 + lm;
            bf16x4 p;
#pragma unroll
            for (int r = 0; r < 4; ++r) p[r] = (bf16)xacc[ct][r];
            *(bf16x4*)&Xt_out[(size_t)b * 65536 + (size_t)dd * 1024 + n0 + wv * 16 + q * 4] = p;
        }
    } else {
        // P2 = muHi@WHi + muLo@WHi + muHi@WLo  (split-precision head GEMM)
#pragma unroll
        for (int s = 0; s < 2; ++s) {
            const int aoff = (wv * 16 + lm) * MS_STRIDE + s * 32 + q * 8;
            bf16x8 aHi = *(const bf16x8*)&muHi[aoff];
            bf16x8 aLo = *(const bf16x8*)&muLo[aoff];
#pragma unroll
            for (int ct = 0; ct < 4; ++ct) {
                const int boff = (ct * 16 + lm) * MS_STRIDE + s * 32 + q * 8;
                bf16x8 bHi = *(const bf16x8*)&WHi[boff];
                bf16x8 bLo = *(const bf16x8*)&WLo[boff];
                xacc[ct] = __builtin_amdgcn_mfma_f32_16x16x32_bf16(aHi, bHi, xacc[ct], 0, 0, 0);
                xacc[ct] = __builtin_amdgcn_mfma_f32_16x16x32_bf16(aLo, bHi, xacc[ct], 0, 0, 0);
                xacc[ct] = __builtin_amdgcn_mfma_f32_16x16x32_bf16(aHi, bLo, xacc[ct], 0, 0, 0);
            }
        }
        // xacc[ct][r] = P2[n = n0+wv*16+q*4+r][h = ct*16+lm]
        const float bq0 = bq[0];
        float rowsum[4] = {0.f, 0.f, 0.f, 0.f};
#pragma unroll
        for (int ct = 0; ct < 4; ++ct) {
            const int h = ct * 16 + lm;
            const float c2 = c2base[b * 64 + h];
            const float wqh = Wq[h];
#pragma unroll
            for (int r = 0; r < 4; ++r)
                rowsum[r] += fmaxf(xacc[ct][r] + c2, 0.f) * wqh;
        }
#pragma unroll
        for (int r = 0; r < 4; ++r) {
            float v = rowsum[r];
            v += __shfl_xor(v, 1);
            v += __shfl_xor(v, 2);
            v += __shfl_xor(v, 4);
            v += __shfl_xor(v, 8);
            if (lm == 0) {
                const int n = n0 + wv * 16 + q * 4 + r;
                out[(size_t)b * (Nc + 1) + n] = v + bq0;
            }
        }
    }
}

// ---------------------------------------------------------------------------
// k_tail: the mean row.  mean = musum/N; meanpost = relu(bq1 + mean@Wq1^T);
//         out[b,N] = bq + sum_h relu(meanpost@Wreg[:,:64]^T + c2base[b,h])*Wq[h]
// grid B, block 64 (all fp32)
// ---------------------------------------------------------------------------
__global__ void k_tail(const float* __restrict__ musum, const float* __restrict__ Wq1,
                       const float* __restrict__ bq1, const float* __restrict__ Wreg,
                       const float* __restrict__ c2base, const float* __restrict__ Wq,
                       const float* __restrict__ bq, float* __restrict__ out) {
    const int b = blockIdx.x, l = threadIdx.x;
    __shared__ float mean_s[64];
    __shared__ float mp[64];
    mean_s[l] = musum[b * 64 + l] * (1.f / Nc);
    __syncthreads();
    float a = bq1[l];
#pragma unroll
    for (int e = 0; e < 64; ++e) a = fmaf(mean_s[e], Wq1[l * 64 + e], a);
    mp[l] = fmaxf(a, 0.f);
    __syncthreads();
    float h = c2base[b * 64 + l];
#pragma unroll
    for (int d = 0; d < 64; ++d) h = fmaf(mp[d], Wreg[l * 128 + d], h);
    float v = fmaxf(h, 0.f) * Wq[l];
#pragma unroll
    for (int off = 32; off; off >>= 1) v += __shfl_down(v, off);
    if (l == 0) out[(size_t)b * (Nc + 1) + Nc] = v + bq[0];
}

// ---------------------------------------------------------------------------
extern "C" void kernel_launch(void* const* d_in, const int* in_sizes, int n_in,
                              void* d_out, int out_size, void* d_ws, size_t ws_size,
                              hipStream_t stream) {
    const float* xv     = (const float*)d_in[0];
    const float* option = (const float*)d_in[1];
    const float* adj    = (const float*)d_in[2];
    const float* mu1w   = (const float*)d_in[3];
    const float* W2     = (const float*)d_in[4];
    const float* b2     = (const float*)d_in[5];
    const float* W3     = (const float*)d_in[6];
    const float* b3     = (const float*)d_in[7];
    const float* W4     = (const float*)d_in[8];
    const float* b4     = (const float*)d_in[9];
    const float* Wq1    = (const float*)d_in[10];
    const float* bq1    = (const float*)d_in[11];
    const float* Wq2    = (const float*)d_in[12];
    const float* bq2    = (const float*)d_in[13];
    const float* Wreg   = (const float*)d_in[14];
    const float* breg   = (const float*)d_in[15];
    const float* Wq     = (const float*)d_in[16];
    const float* bq     = (const float*)d_in[17];
    float* out = (float*)d_out;

    float* ws = (float*)d_ws;
    const size_t MU = (size_t)Bc * Nc * Dc;          // 2,097,152
    float* mu_1     = ws;
    float* C3       = ws + MU;                       // 65536
    float* c2base   = C3 + 65536;                    // 2048
    float* musum    = c2base + 2048;                 // 2048
    bf16*  Abf      = (bf16*)(musum + 2048);         // 1M bf16
    bf16*  W2bf     = Abf + (size_t)Nc * Nc;         // 4096 bf16
    bf16*  Xt0      = W2bf + 4096;                   // B*D*N bf16
    bf16*  Xt1      = Xt0 + MU;

    k_prep<<<1026, 256, 0, stream>>>(adj, W2, option, Wq2, bq2, Wreg, breg,
                                     Abf, W2bf, c2base, musum);
    k_c3<<<Nc, 256, 0, stream>>>(adj, W4, b4, W3, b3, b2, C3);
    k_mu1<<<dim3(Nc / 64, Bc), 256, 0, stream>>>(xv, mu1w, W2bf, mu_1, Xt0);
    k_round<false><<<dim3(Nc / 64, Bc), 256, LDS_NONF, stream>>>(
        Abf, Xt0, mu_1, C3, W2bf, Xt1,
        nullptr, nullptr, nullptr, nullptr, nullptr, nullptr);
    k_round<false><<<dim3(Nc / 64, Bc), 256, LDS_NONF, stream>>>(
        Abf, Xt1, mu_1, C3, W2bf, Xt0,
        nullptr, nullptr, nullptr, nullptr, nullptr, nullptr);
    k_round<true><<<dim3(Nc / 64, Bc), 256, LDS_FIN, stream>>>(
        Abf, Xt0, mu_1, C3, nullptr, nullptr,
        Wreg, c2base, Wq, bq, musum, out);
    k_tail<<<Bc, 64, 0, stream>>>(musum, Wq1, bq1, Wreg, c2base, Wq, bq, out);
}

// Round 5
// 175.056 us; speedup vs baseline: 3.4717x; 1.0225x over previous
//
#include <hip/hip_runtime.h>
#include <hip/hip_bf16.h>

#define Bc 32
#define Nc 1024
#define Fc 32
#define Dc 64
#define Hc 64

typedef __bf16 bf16;
typedef __bf16 bf16x4 __attribute__((ext_vector_type(4)));
typedef __bf16 bf16x8 __attribute__((ext_vector_type(8)));
typedef float  f32x4  __attribute__((ext_vector_type(4)));

#define AS_STRIDE 136   // bf16 elements; 272B rows (16B-aligned), uniform bank spread
#define MS_STRIDE 72    // bf16 elements; 144B rows (16B-aligned)
#define LDS_MAIN  (2 * 64 * AS_STRIDE * 2)                 // As + Xs       = 34816 B
#define LDS_NONF  (LDS_MAIN + 2 * 64 * MS_STRIDE * 2)      // + muHi + WHi  = 53248 B
#define LDS_FIN   (LDS_NONF + 2 * 64 * MS_STRIDE * 2)      // + muLo + WLo  = 71680 B

// ---------------------------------------------------------------------------
// k_prep: Abf[n][m] = (adj[n][m] > 0) as bf16 {0,1};  W2bf = bf16(W2);
//         block 1025: c2base[b,h] = breg[h] + sum_j (option[b]*Wq2[j]+bq2[j])*Wreg[h,64+j]
//                     and zero musum
// grid 1026, block 256
// ---------------------------------------------------------------------------
__global__ void k_prep(const float* __restrict__ adj, const float* __restrict__ W2,
                       const float* __restrict__ option, const float* __restrict__ Wq2,
                       const float* __restrict__ bq2, const float* __restrict__ Wreg,
                       const float* __restrict__ breg,
                       bf16* __restrict__ Abf, bf16* __restrict__ W2bf,
                       float* __restrict__ c2base, float* __restrict__ musum) {
    const int t = threadIdx.x;
    if (blockIdx.x < 1024) {
        const int i = blockIdx.x * 1024 + t * 4;
        const float4 a = *(const float4*)&adj[i];
        bf16x4 o;
        o[0] = (bf16)((a.x > 0.f) ? 1.f : 0.f);
        o[1] = (bf16)((a.y > 0.f) ? 1.f : 0.f);
        o[2] = (bf16)((a.z > 0.f) ? 1.f : 0.f);
        o[3] = (bf16)((a.w > 0.f) ? 1.f : 0.f);
        *(bf16x4*)&Abf[i] = o;
    } else if (blockIdx.x == 1024) {
        for (int j = t * 16; j < t * 16 + 16; ++j) W2bf[j] = (bf16)W2[j];
    } else {
        for (int i = t; i < 2048; i += 256) musum[i] = 0.f;
        for (int i = t; i < 2048; i += 256) {
            const int b = i >> 6, h = i & 63;
            const float opt = option[b];
            float a = breg[h];
#pragma unroll
            for (int j = 0; j < 64; ++j)
                a = fmaf(fmaf(opt, Wq2[j], bq2[j]), Wreg[h * 128 + 64 + j], a);
            c2base[i] = a;
        }
    }
}

// ---------------------------------------------------------------------------
// k_c3: C3[n,d] = b2[d] + b3[d] + sum_e mu4[n,e]*W3[d,e]
// grid N, block 256
// ---------------------------------------------------------------------------
__global__ void k_c3(const float* __restrict__ adj, const float* __restrict__ W4,
                     const float* __restrict__ b4, const float* __restrict__ W3,
                     const float* __restrict__ b3, const float* __restrict__ b2,
                     float* __restrict__ C3) {
    const int n = blockIdx.x, t = threadIdx.x;
    const int e = t & 63, g = t >> 6;
    __shared__ float red[256];
    __shared__ float mu4_s[64];
    const float w4e = W4[e], b4e = b4[e];
    const float* arow = adj + (size_t)n * Nc;
    float acc = 0.f;
    for (int m = g * 256; m < g * 256 + 256; ++m)
        acc += fmaxf(fmaf(arow[m], w4e, b4e), 0.f);
    red[t] = acc;
    __syncthreads();
    if (g == 0) mu4_s[e] = red[e] + red[64 + e] + red[128 + e] + red[192 + e];
    __syncthreads();
    if (t < 64) {
        const int d = t;
        float a = b3[d] + b2[d];
        for (int ee = 0; ee < 64; ++ee) a = fmaf(mu4_s[ee], W3[d * 64 + ee], a);
        C3[n * 64 + d] = a;
    }
}

// ---------------------------------------------------------------------------
// k_mu1: mu_1 = relu(xv@mu1) (fp32 out) AND X0 = mu_1 @ W2^T as bf16 [b][d][n]
// grid (N/64, B), block 256
// ---------------------------------------------------------------------------
__global__ void k_mu1(const float* __restrict__ xv, const float* __restrict__ w,
                      const bf16* __restrict__ W2bf,
                      float* __restrict__ mu_1, bf16* __restrict__ Xt) {
    const int nb = blockIdx.x, b = blockIdx.y, t = threadIdx.x;
    const int n0 = nb * 64;
    __shared__ float w_s[Fc * Dc];
    __shared__ float x_s[64 * 33];
    __shared__ bf16  muS[64 * MS_STRIDE];
    __shared__ bf16  W2s[64 * MS_STRIDE];
    for (int i = t; i < Fc * Dc; i += 256) w_s[i] = w[i];
    for (int i = t; i < 64 * Fc; i += 256) {
        int r = i >> 5, f = i & 31;
        x_s[r * 33 + f] = xv[((size_t)b * Nc + n0 + r) * Fc + f];
    }
#pragma unroll
    for (int i = 0; i < 2; ++i) {
        int g = i * 256 + t, row = g >> 3, c = g & 7;
        *(bf16x8*)&W2s[row * MS_STRIDE + c * 8] = *(const bf16x8*)&W2bf[row * 64 + c * 8];
    }
    __syncthreads();
    const int d = t & 63, rg = t >> 6;
    for (int ri = 0; ri < 16; ++ri) {
        int r = rg * 16 + ri;
        float acc = 0.f;
#pragma unroll
        for (int f = 0; f < Fc; ++f) acc = fmaf(x_s[r * 33 + f], w_s[f * Dc + d], acc);
        acc = fmaxf(acc, 0.f);
        mu_1[((size_t)b * Nc + n0 + r) * Dc + d] = acc;
        muS[r * MS_STRIDE + d] = (bf16)acc;
    }
    __syncthreads();
    const int l = t & 63, wv = t >> 6, lm = l & 15, q = l >> 4;
    f32x4 xacc[4];
#pragma unroll
    for (int ct = 0; ct < 4; ++ct)
#pragma unroll
        for (int r = 0; r < 4; ++r) xacc[ct][r] = 0.f;
#pragma unroll
    for (int s = 0; s < 2; ++s) {
        bf16x8 a = *(const bf16x8*)&muS[(wv * 16 + lm) * MS_STRIDE + s * 32 + q * 8];
#pragma unroll
        for (int ct = 0; ct < 4; ++ct) {
            bf16x8 bv = *(const bf16x8*)&W2s[(ct * 16 + lm) * MS_STRIDE + s * 32 + q * 8];
            xacc[ct] = __builtin_amdgcn_mfma_f32_16x16x32_bf16(a, bv, xacc[ct], 0, 0, 0);
        }
    }
#pragma unroll
    for (int ct = 0; ct < 4; ++ct) {
        const int dd = ct * 16 + lm;
        bf16x4 p;
#pragma unroll
        for (int r = 0; r < 4; ++r) p[r] = (bf16)xacc[ct][r];
        *(bf16x4*)&Xt[(size_t)b * 65536 + (size_t)dd * 1024 + n0 + wv * 16 + q * 4] = p;
    }
}

// ---------------------------------------------------------------------------
// k_round: P = A_tile @ X (MFMA, K=1024) with REGISTER-PREFETCH pipeline,
//          mu = relu(mu_1 + P + C3), then:
//   non-final: X_out = mu @ W2^T (MFMA) as bf16 [b][d][n]
//   final:     out[b,n] = bq + sum_h relu((mu @ Wreg[:,:64]^T)[n,h] + c2base[b,h])*Wq[h]
//              via split-precision bf16 MFMA, plus musum[b,d] atomics for the mean row
// grid (B, N/64): b = blockIdx.x (XCD-pinned X[b] L2 locality), nb = blockIdx.y
// block 256 = 4 waves; dynamic LDS: LDS_NONF / LDS_FIN bytes
// ---------------------------------------------------------------------------
template <bool FINAL>
__global__ __launch_bounds__(256, 2)
void k_round(const bf16* __restrict__ Abf, const bf16* __restrict__ Xt_in,
             const float* __restrict__ mu_1, const float* __restrict__ C3,
             const bf16* __restrict__ W2bf, bf16* __restrict__ Xt_out,
             const float* __restrict__ Wreg, const float* __restrict__ c2base,
             const float* __restrict__ Wq, const float* __restrict__ bq,
             float* __restrict__ musum, float* __restrict__ out) {
    const int b = blockIdx.x, nb = blockIdx.y, t = threadIdx.x;
    const int n0 = nb * 64;
    const int l = t & 63, wv = t >> 6, lm = l & 15, q = l >> 4;
    extern __shared__ char smem[];
    bf16* As   = (bf16*)smem;                 // 64*AS_STRIDE
    bf16* Xs   = As + 64 * AS_STRIDE;         // 64*AS_STRIDE
    bf16* muHi = Xs + 64 * AS_STRIDE;         // 64*MS_STRIDE
    bf16* WHi  = muHi + 64 * MS_STRIDE;       // 64*MS_STRIDE (non-final: W2bf)
    bf16* muLo = WHi + 64 * MS_STRIDE;        // FINAL only
    bf16* WLo  = muLo + 64 * MS_STRIDE;       // FINAL only

    if (!FINAL) {
#pragma unroll
        for (int i = 0; i < 2; ++i) {
            int g = i * 256 + t, row = g >> 3, c = g & 7;
            *(bf16x8*)&WHi[row * MS_STRIDE + c * 8] = *(const bf16x8*)&W2bf[row * 64 + c * 8];
        }
    } else {
        // stage Wreg[h][d<64] as hi/lo bf16
#pragma unroll
        for (int i = 0; i < 4; ++i) {
            int g = i * 1024 + t * 4;
            int h = g >> 6, d = g & 63;
            const float4 w4 = *(const float4*)&Wreg[h * 128 + d];
            bf16x4 ohi, olo;
            ohi[0] = (bf16)w4.x; olo[0] = (bf16)(w4.x - (float)ohi[0]);
            ohi[1] = (bf16)w4.y; olo[1] = (bf16)(w4.y - (float)ohi[1]);
            ohi[2] = (bf16)w4.z; olo[2] = (bf16)(w4.z - (float)ohi[2]);
            ohi[3] = (bf16)w4.w; olo[3] = (bf16)(w4.w - (float)ohi[3]);
            *(bf16x4*)&WHi[h * MS_STRIDE + d] = ohi;
            *(bf16x4*)&WLo[h * MS_STRIDE + d] = olo;
        }
    }

    f32x4 acc[4];
#pragma unroll
    for (int ct = 0; ct < 4; ++ct)
#pragma unroll
        for (int r = 0; r < 4; ++r) acc[ct][r] = 0.f;

    const bf16* Arow = Abf + (size_t)n0 * 1024;
    const bf16* Xrow = Xt_in + (size_t)b * 65536;

    // register prefetch of tile kc=0
    bf16x8 pa[4], px[4];
#pragma unroll
    for (int i = 0; i < 4; ++i) {
        int g = i * 256 + t, row = g >> 4, c = g & 15;
        pa[i] = *(const bf16x8*)&Arow[(size_t)row * 1024 + c * 8];
        px[i] = *(const bf16x8*)&Xrow[(size_t)row * 1024 + c * 8];
    }

    for (int kc = 0; kc < 1024; kc += 128) {
        __syncthreads();   // previous iteration's ds_reads done before overwrite
#pragma unroll
        for (int i = 0; i < 4; ++i) {
            int g = i * 256 + t, row = g >> 4, c = g & 15;
            *(bf16x8*)&As[row * AS_STRIDE + c * 8] = pa[i];
            *(bf16x8*)&Xs[row * AS_STRIDE + c * 8] = px[i];
        }
        __syncthreads();
        if (kc + 128 < 1024) {
            // prefetch next tile; latency hidden behind the MFMA phase below
#pragma unroll
            for (int i = 0; i < 4; ++i) {
                int g = i * 256 + t, row = g >> 4, c = g & 15;
                pa[i] = *(const bf16x8*)&Arow[(size_t)row * 1024 + kc + 128 + c * 8];
                px[i] = *(const bf16x8*)&Xrow[(size_t)row * 1024 + kc + 128 + c * 8];
            }
        }
#pragma unroll
        for (int s = 0; s < 4; ++s) {
            bf16x8 a = *(const bf16x8*)&As[(wv * 16 + lm) * AS_STRIDE + s * 32 + q * 8];
#pragma unroll
            for (int ct = 0; ct < 4; ++ct) {
                bf16x8 bv = *(const bf16x8*)&Xs[(ct * 16 + lm) * AS_STRIDE + s * 32 + q * 8];
                acc[ct] = __builtin_amdgcn_mfma_f32_16x16x32_bf16(a, bv, acc[ct], 0, 0, 0);
            }
        }
    }

    // epilogue: mu = relu(mu_1 + P + C3).  C/D: col = lane&15 (+16*ct), row = q*4+r (+16w)
    float vals[4][4];
#pragma unroll
    for (int ct = 0; ct < 4; ++ct) {
        const int col = ct * 16 + lm;
#pragma unroll
        for (int r = 0; r < 4; ++r) {
            const int n = n0 + wv * 16 + q * 4 + r;
            float v = mu_1[((size_t)b * Nc + n) * Dc + col] + acc[ct][r] + C3[n * 64 + col];
            vals[ct][r] = fmaxf(v, 0.f);
        }
    }

    __syncthreads();   // K-loop ds_reads done before muHi writes share the LDS phase
    // write mu tile to LDS as bf16 [n][d] (FINAL: hi/lo split)
#pragma unroll
    for (int ct = 0; ct < 4; ++ct) {
        const int col = ct * 16 + lm;
#pragma unroll
        for (int r = 0; r < 4; ++r) {
            const int row = wv * 16 + q * 4 + r;
            const float v = vals[ct][r];
            const bf16 hi = (bf16)v;
            muHi[row * MS_STRIDE + col] = hi;
            if (FINAL) muLo[row * MS_STRIDE + col] = (bf16)(v - (float)hi);
        }
    }

    if (FINAL) {
        // musum[b,d] += sum over this wave's 16 rows (fp32 values)
#pragma unroll
        for (int ct = 0; ct < 4; ++ct) {
            float s = vals[ct][0] + vals[ct][1] + vals[ct][2] + vals[ct][3];
            s += __shfl_xor(s, 16);
            s += __shfl_xor(s, 32);
            if (q == 0) atomicAdd(&musum[b * 64 + ct * 16 + lm], s);
        }
    }

    __syncthreads();
    f32x4 xacc[4];
#pragma unroll
    for (int ct = 0; ct < 4; ++ct)
#pragma unroll
        for (int r = 0; r < 4; ++r) xacc[ct][r] = 0.f;

    if (!FINAL) {
#pragma unroll
        for (int s = 0; s < 2; ++s) {
            bf16x8 a = *(const bf16x8*)&muHi[(wv * 16 + lm) * MS_STRIDE + s * 32 + q * 8];
#pragma unroll
            for (int ct = 0; ct < 4; ++ct) {
                bf16x8 bv = *(const bf16x8*)&WHi[(ct * 16 + lm) * MS_STRIDE + s * 32 + q * 8];
                xacc[ct] = __builtin_amdgcn_mfma_f32_16x16x32_bf16(a, bv, xacc[ct], 0, 0, 0);
            }
        }
#pragma unroll
        for (int ct = 0; ct < 4; ++ct) {
            const int dd = ct * 16 + lm;
            bf16x4 p;
#pragma unroll
            for (int r = 0; r < 4; ++r) p[r] = (bf16)xacc[ct][r];
            *(bf16x4*)&Xt_out[(size_t)b * 65536 + (size_t)dd * 1024 + n0 + wv * 16 + q * 4] = p;
        }
    } else {
        // P2 = muHi@WHi + muLo@WHi + muHi@WLo  (split-precision head GEMM)
#pragma unroll
        for (int s = 0; s < 2; ++s) {
            const int aoff = (wv * 16 + lm) * MS_STRIDE + s * 32 + q * 8;
            bf16x8 aHi = *(const bf16x8*)&muHi[aoff];
            bf16x8 aLo = *(const bf16x8*)&muLo[aoff];
#pragma unroll
            for (int ct = 0; ct < 4; ++ct) {
                const int boff = (ct * 16 + lm) * MS_STRIDE + s * 32 + q * 8;
                bf16x8 bHi = *(const bf16x8*)&WHi[boff];
                bf16x8 bLo = *(const bf16x8*)&WLo[boff];
                xacc[ct] = __builtin_amdgcn_mfma_f32_16x16x32_bf16(aHi, bHi, xacc[ct], 0, 0, 0);
                xacc[ct] = __builtin_amdgcn_mfma_f32_16x16x32_bf16(aLo, bHi, xacc[ct], 0, 0, 0);
                xacc[ct] = __builtin_amdgcn_mfma_f32_16x16x32_bf16(aHi, bLo, xacc[ct], 0, 0, 0);
            }
        }
        // xacc[ct][r] = P2[n = n0+wv*16+q*4+r][h = ct*16+lm]
        const float bq0 = bq[0];
        float rowsum[4] = {0.f, 0.f, 0.f, 0.f};
#pragma unroll
        for (int ct = 0; ct < 4; ++ct) {
            const int h = ct * 16 + lm;
            const float c2 = c2base[b * 64 + h];
            const float wqh = Wq[h];
#pragma unroll
            for (int r = 0; r < 4; ++r)
                rowsum[r] += fmaxf(xacc[ct][r] + c2, 0.f) * wqh;
        }
#pragma unroll
        for (int r = 0; r < 4; ++r) {
            float v = rowsum[r];
            v += __shfl_xor(v, 1);
            v += __shfl_xor(v, 2);
            v += __shfl_xor(v, 4);
            v += __shfl_xor(v, 8);
            if (lm == 0) {
                const int n = n0 + wv * 16 + q * 4 + r;
                out[(size_t)b * (Nc + 1) + n] = v + bq0;
            }
        }
    }
}

// ---------------------------------------------------------------------------
// k_tail: the mean row.  mean = musum/N; meanpost = relu(bq1 + mean@Wq1^T);
//         out[b,N] = bq + sum_h relu(meanpost@Wreg[:,:64]^T + c2base[b,h])*Wq[h]
// grid B, block 64 (all fp32)
// ---------------------------------------------------------------------------
__global__ void k_tail(const float* __restrict__ musum, const float* __restrict__ Wq1,
                       const float* __restrict__ bq1, const float* __restrict__ Wreg,
                       const float* __restrict__ c2base, const float* __restrict__ Wq,
                       const float* __restrict__ bq, float* __restrict__ out) {
    const int b = blockIdx.x, l = threadIdx.x;
    __shared__ float mean_s[64];
    __shared__ float mp[64];
    mean_s[l] = musum[b * 64 + l] * (1.f / Nc);
    __syncthreads();
    float a = bq1[l];
#pragma unroll
    for (int e = 0; e < 64; ++e) a = fmaf(mean_s[e], Wq1[l * 64 + e], a);
    mp[l] = fmaxf(a, 0.f);
    __syncthreads();
    float h = c2base[b * 64 + l];
#pragma unroll
    for (int d = 0; d < 64; ++d) h = fmaf(mp[d], Wreg[l * 128 + d], h);
    float v = fmaxf(h, 0.f) * Wq[l];
#pragma unroll
    for (int off = 32; off; off >>= 1) v += __shfl_down(v, off);
    if (l == 0) out[(size_t)b * (Nc + 1) + Nc] = v + bq[0];
}

// ---------------------------------------------------------------------------
extern "C" void kernel_launch(void* const* d_in, const int* in_sizes, int n_in,
                              void* d_out, int out_size, void* d_ws, size_t ws_size,
                              hipStream_t stream) {
    const float* xv     = (const float*)d_in[0];
    const float* option = (const float*)d_in[1];
    const float* adj    = (const float*)d_in[2];
    const float* mu1w   = (const float*)d_in[3];
    const float* W2     = (const float*)d_in[4];
    const float* b2     = (const float*)d_in[5];
    const float* W3     = (const float*)d_in[6];
    const float* b3     = (const float*)d_in[7];
    const float* W4     = (const float*)d_in[8];
    const float* b4     = (const float*)d_in[9];
    const float* Wq1    = (const float*)d_in[10];
    const float* bq1    = (const float*)d_in[11];
    const float* Wq2    = (const float*)d_in[12];
    const float* bq2    = (const float*)d_in[13];
    const float* Wreg   = (const float*)d_in[14];
    const float* breg   = (const float*)d_in[15];
    const float* Wq     = (const float*)d_in[16];
    const float* bq     = (const float*)d_in[17];
    float* out = (float*)d_out;

    float* ws = (float*)d_ws;
    const size_t MU = (size_t)Bc * Nc * Dc;          // 2,097,152
    float* mu_1     = ws;
    float* C3       = ws + MU;                       // 65536
    float* c2base   = C3 + 65536;                    // 2048
    float* musum    = c2base + 2048;                 // 2048
    bf16*  Abf      = (bf16*)(musum + 2048);         // 1M bf16
    bf16*  W2bf     = Abf + (size_t)Nc * Nc;         // 4096 bf16
    bf16*  Xt0      = W2bf + 4096;                   // B*D*N bf16
    bf16*  Xt1      = Xt0 + MU;

    k_prep<<<1026, 256, 0, stream>>>(adj, W2, option, Wq2, bq2, Wreg, breg,
                                     Abf, W2bf, c2base, musum);
    k_c3<<<Nc, 256, 0, stream>>>(adj, W4, b4, W3, b3, b2, C3);
    k_mu1<<<dim3(Nc / 64, Bc), 256, 0, stream>>>(xv, mu1w, W2bf, mu_1, Xt0);
    k_round<false><<<dim3(Bc, Nc / 64), 256, LDS_NONF, stream>>>(
        Abf, Xt0, mu_1, C3, W2bf, Xt1,
        nullptr, nullptr, nullptr, nullptr, nullptr, nullptr);
    k_round<false><<<dim3(Bc, Nc / 64), 256, LDS_NONF, stream>>>(
        Abf, Xt1, mu_1, C3, W2bf, Xt0,
        nullptr, nullptr, nullptr, nullptr, nullptr, nullptr);
    k_round<true><<<dim3(Bc, Nc / 64), 256, LDS_FIN, stream>>>(
        Abf, Xt0, mu_1, C3, nullptr, nullptr,
        Wreg, c2base, Wq, bq, musum, out);
    k_tail<<<Bc, 64, 0, stream>>>(musum, Wq1, bq1, Wreg, c2base, Wq, bq, out);
}

// Round 6
// 159.339 us; speedup vs baseline: 3.8142x; 1.0986x over previous
//
#include <hip/hip_runtime.h>
#include <hip/hip_bf16.h>

#define Bc 32
#define Nc 1024
#define Fc 32
#define Dc 64
#define Hc 64

typedef __bf16 bf16;
typedef __bf16 bf16x4 __attribute__((ext_vector_type(4)));
typedef __bf16 bf16x8 __attribute__((ext_vector_type(8)));
typedef float  f32x4  __attribute__((ext_vector_type(4)));

#define AS_STRIDE 136   // bf16; 272B rows: 16B-aligned, 2-way bank alias only (free)
#define MS_STRIDE 72    // bf16; 144B rows

// k_round LDS layout (bytes), dynamic:
//   K-phase:   As [32*136*2 = 8704) | Xs [8704, 26112)
//   epilogue (aliased): muHi [0,4608) | WHi [4608,13824)
//   FINAL extra:        muLo [13824,18432) | WLo [18432,27648) | rpart [27648,27904)
#define LDS_RND_NONF 26112
#define LDS_RND_FIN  27904

// ---------------------------------------------------------------------------
// k_pc: blocks 0..1023 (n = blockIdx.x):
//   Abf[n][m] = (adj[n][m] > 0) bf16; C3[n][d] = b2+b3 + sum_e mu4[n][e] W3[d][e]
// block 1024: W2bf = bf16(W2); zero musum; c2base[b][h]
// ---------------------------------------------------------------------------
__global__ void k_pc(const float* __restrict__ adj, const float* __restrict__ W4,
                     const float* __restrict__ b4, const float* __restrict__ W3,
                     const float* __restrict__ b3, const float* __restrict__ b2,
                     const float* __restrict__ W2, const float* __restrict__ option,
                     const float* __restrict__ Wq2, const float* __restrict__ bq2,
                     const float* __restrict__ Wreg, const float* __restrict__ breg,
                     bf16* __restrict__ Abf, float* __restrict__ C3,
                     bf16* __restrict__ W2bf, float* __restrict__ c2base,
                     float* __restrict__ musum) {
    const int t = threadIdx.x;
    if (blockIdx.x < 1024) {
        const int n = blockIdx.x;
        const float* arow = adj + (size_t)n * Nc;
        // binarize: 4 elements per thread
        {
            const float4 a = *(const float4*)&arow[t * 4];
            bf16x4 o;
            o[0] = (bf16)((a.x > 0.f) ? 1.f : 0.f);
            o[1] = (bf16)((a.y > 0.f) ? 1.f : 0.f);
            o[2] = (bf16)((a.z > 0.f) ? 1.f : 0.f);
            o[3] = (bf16)((a.w > 0.f) ? 1.f : 0.f);
            *(bf16x4*)&Abf[(size_t)n * Nc + t * 4] = o;
        }
        // mu4[e] = sum_m relu(arow[m]*W4[e] + b4[e]) ; 4 m-groups of 256
        const int e = t & 63, g = t >> 6;
        __shared__ float red[256];
        __shared__ float mu4_s[64];
        const float w4e = W4[e], b4e = b4[e];
        float acc = 0.f;
        const float4* arow4 = (const float4*)(arow + g * 256);
#pragma unroll 8
        for (int j = 0; j < 64; ++j) {          // same addr across wave -> broadcast
            const float4 av = arow4[j];
            acc += fmaxf(fmaf(av.x, w4e, b4e), 0.f);
            acc += fmaxf(fmaf(av.y, w4e, b4e), 0.f);
            acc += fmaxf(fmaf(av.z, w4e, b4e), 0.f);
            acc += fmaxf(fmaf(av.w, w4e, b4e), 0.f);
        }
        red[t] = acc;
        __syncthreads();
        if (g == 0) mu4_s[e] = red[e] + red[64 + e] + red[128 + e] + red[192 + e];
        __syncthreads();
        if (t < 64) {
            const int d = t;
            float a = b3[d] + b2[d];
#pragma unroll
            for (int ee = 0; ee < 64; ++ee) a = fmaf(mu4_s[ee], W3[d * 64 + ee], a);
            C3[n * 64 + d] = a;
        }
    } else {
        for (int j = t * 16; j < t * 16 + 16; ++j) W2bf[j] = (bf16)W2[j];
        for (int i = t; i < 2048; i += 256) musum[i] = 0.f;
        for (int i = t; i < 2048; i += 256) {
            const int b = i >> 6, h = i & 63;
            const float opt = option[b];
            float a = breg[h];
#pragma unroll
            for (int j = 0; j < 64; ++j)
                a = fmaf(fmaf(opt, Wq2[j], bq2[j]), Wreg[h * 128 + 64 + j], a);
            c2base[i] = a;
        }
    }
}

// ---------------------------------------------------------------------------
// k_mu1: mu_1 = relu(xv@mu1) via split-precision MFMA (fp32-quality), fp32 out,
//        AND X0 = bf16(mu_1) @ W2^T as bf16 [b][d][n]
// grid (N/64, B), block 256 = 4 waves; wave w: rows 16w..16w+15, cols 0..63
// ---------------------------------------------------------------------------
__global__ void k_mu1(const float* __restrict__ xv, const float* __restrict__ w,
                      const bf16* __restrict__ W2bf,
                      float* __restrict__ mu_1, bf16* __restrict__ Xt) {
    const int nb = blockIdx.x, b = blockIdx.y, t = threadIdx.x;
    const int n0 = nb * 64;
    const int l = t & 63, wv = t >> 6, lm = l & 15, q = l >> 4;
    __shared__ bf16 xhi[64 * 40], xlo[64 * 40];   // [row][f], pad to 40
    __shared__ bf16 whi[64 * 40], wlo[64 * 40];   // [d][f]
    __shared__ bf16 muS[64 * MS_STRIDE];
    __shared__ bf16 W2s[64 * MS_STRIDE];

    // stage xv tile hi/lo: 8 floats per thread
    {
        const int row = t >> 2, f0 = (t & 3) * 8;
        const float* src = &xv[((size_t)b * Nc + n0 + row) * Fc + f0];
        const float4 v0 = *(const float4*)src;
        const float4 v1 = *(const float4*)(src + 4);
        bf16x8 hi, lo;
        float vv[8] = {v0.x, v0.y, v0.z, v0.w, v1.x, v1.y, v1.z, v1.w};
#pragma unroll
        for (int j = 0; j < 8; ++j) { hi[j] = (bf16)vv[j]; lo[j] = (bf16)(vv[j] - (float)hi[j]); }
        *(bf16x8*)&xhi[row * 40 + f0] = hi;
        *(bf16x8*)&xlo[row * 40 + f0] = lo;
    }
    // stage w transposed [d][f] hi/lo: 8 scalars per thread
    {
        const int d = t >> 2, f0 = (t & 3) * 8;
#pragma unroll
        for (int j = 0; j < 8; ++j) {
            const float v = w[(f0 + j) * Dc + d];
            const bf16 hi = (bf16)v;
            whi[d * 40 + f0 + j] = hi;
            wlo[d * 40 + f0 + j] = (bf16)(v - (float)hi);
        }
    }
    // stage W2s[d][e]
#pragma unroll
    for (int i = 0; i < 2; ++i) {
        int g = i * 256 + t, row = g >> 3, c = g & 7;
        *(bf16x8*)&W2s[row * MS_STRIDE + c * 8] = *(const bf16x8*)&W2bf[row * 64 + c * 8];
    }
    __syncthreads();

    // phase 1: mu_1 tile via 3-product split MFMA (K=32 -> 1 MFMA per product)
    f32x4 acc[4];
#pragma unroll
    for (int ct = 0; ct < 4; ++ct)
#pragma unroll
        for (int r = 0; r < 4; ++r) acc[ct][r] = 0.f;
    {
        const bf16x8 aHi = *(const bf16x8*)&xhi[(wv * 16 + lm) * 40 + q * 8];
        const bf16x8 aLo = *(const bf16x8*)&xlo[(wv * 16 + lm) * 40 + q * 8];
#pragma unroll
        for (int ct = 0; ct < 4; ++ct) {
            const bf16x8 bHi = *(const bf16x8*)&whi[(ct * 16 + lm) * 40 + q * 8];
            const bf16x8 bLo = *(const bf16x8*)&wlo[(ct * 16 + lm) * 40 + q * 8];
            acc[ct] = __builtin_amdgcn_mfma_f32_16x16x32_bf16(aHi, bHi, acc[ct], 0, 0, 0);
            acc[ct] = __builtin_amdgcn_mfma_f32_16x16x32_bf16(aLo, bHi, acc[ct], 0, 0, 0);
            acc[ct] = __builtin_amdgcn_mfma_f32_16x16x32_bf16(aHi, bLo, acc[ct], 0, 0, 0);
        }
    }
    // relu, store fp32, write bf16 to muS
#pragma unroll
    for (int ct = 0; ct < 4; ++ct) {
        const int col = ct * 16 + lm;
#pragma unroll
        for (int r = 0; r < 4; ++r) {
            const int row = wv * 16 + q * 4 + r;
            const float v = fmaxf(acc[ct][r], 0.f);
            mu_1[((size_t)b * Nc + n0 + row) * Dc + col] = v;
            muS[row * MS_STRIDE + col] = (bf16)v;
        }
    }
    __syncthreads();
    // phase 2: X0 = muS @ W2s^T
    f32x4 xacc[4];
#pragma unroll
    for (int ct = 0; ct < 4; ++ct)
#pragma unroll
        for (int r = 0; r < 4; ++r) xacc[ct][r] = 0.f;
#pragma unroll
    for (int s = 0; s < 2; ++s) {
        bf16x8 a = *(const bf16x8*)&muS[(wv * 16 + lm) * MS_STRIDE + s * 32 + q * 8];
#pragma unroll
        for (int ct = 0; ct < 4; ++ct) {
            bf16x8 bv = *(const bf16x8*)&W2s[(ct * 16 + lm) * MS_STRIDE + s * 32 + q * 8];
            xacc[ct] = __builtin_amdgcn_mfma_f32_16x16x32_bf16(a, bv, xacc[ct], 0, 0, 0);
        }
    }
#pragma unroll
    for (int ct = 0; ct < 4; ++ct) {
        const int dd = ct * 16 + lm;
        bf16x4 p;
#pragma unroll
        for (int r = 0; r < 4; ++r) p[r] = (bf16)xacc[ct][r];
        *(bf16x4*)&Xt[(size_t)b * 65536 + (size_t)dd * 1024 + n0 + wv * 16 + q * 4] = p;
    }
}

// ---------------------------------------------------------------------------
// k_round: 32-row tiles for occupancy. P = A_tile @ X (K=1024), mu = relu(mu_1+P+C3).
//   non-final: X_out = mu @ W2^T (bf16 [b][d][n])
//   final:     fused head (split-precision) -> out[b,n]; musum atomics for mean row
// grid (B, N/32) = 1024 blocks, 256 thr = 4 waves.
// wave w: rowtile rw = w&1 (rows 16rw..+15 of 32), col-half cth = w>>1 (cols 32cth..+31)
// ---------------------------------------------------------------------------
template <bool FINAL>
__global__ __launch_bounds__(256, 4)
void k_round(const bf16* __restrict__ Abf, const bf16* __restrict__ Xt_in,
             const float* __restrict__ mu_1, const float* __restrict__ C3,
             const bf16* __restrict__ W2bf, bf16* __restrict__ Xt_out,
             const float* __restrict__ Wreg, const float* __restrict__ c2base,
             const float* __restrict__ Wq, const float* __restrict__ bq,
             float* __restrict__ musum, float* __restrict__ out) {
    const int b = blockIdx.x, nb = blockIdx.y, t = threadIdx.x;
    const int n0 = nb * 32;
    const int l = t & 63, wv = t >> 6, lm = l & 15, q = l >> 4;
    const int rw = wv & 1, cth = wv >> 1;
    extern __shared__ char smem[];
    bf16* As   = (bf16*)smem;                  // K-phase [32][AS_STRIDE]
    bf16* Xs   = (bf16*)(smem + 8704);         // K-phase [64][AS_STRIDE]
    bf16* muHi = (bf16*)smem;                  // epilogue (aliased) [32][MS_STRIDE]
    bf16* WHi  = (bf16*)(smem + 4608);         // [64][MS_STRIDE]
    bf16* muLo = (bf16*)(smem + 13824);        // FINAL
    bf16* WLo  = (bf16*)(smem + 18432);        // FINAL
    float* rpart = (float*)(smem + 27648);     // FINAL [2][32]

    // pre-load epilogue weights into registers (written to LDS post-K-loop)
    bf16x8 pw[2];
    bf16x4 wrhi[4], wrlo[4];
    if (!FINAL) {
#pragma unroll
        for (int i = 0; i < 2; ++i) {
            int g = i * 256 + t, row = g >> 3, c = g & 7;
            pw[i] = *(const bf16x8*)&W2bf[row * 64 + c * 8];
        }
    } else {
#pragma unroll
        for (int i = 0; i < 4; ++i) {
            int g = i * 1024 + t * 4;
            int h = g >> 6, d = g & 63;
            const float4 w4 = *(const float4*)&Wreg[h * 128 + d];
            wrhi[i][0] = (bf16)w4.x; wrlo[i][0] = (bf16)(w4.x - (float)wrhi[i][0]);
            wrhi[i][1] = (bf16)w4.y; wrlo[i][1] = (bf16)(w4.y - (float)wrhi[i][1]);
            wrhi[i][2] = (bf16)w4.z; wrlo[i][2] = (bf16)(w4.z - (float)wrhi[i][2]);
            wrhi[i][3] = (bf16)w4.w; wrlo[i][3] = (bf16)(w4.w - (float)wrhi[i][3]);
        }
    }

    f32x4 acc[2];
#pragma unroll
    for (int ct = 0; ct < 2; ++ct)
#pragma unroll
        for (int r = 0; r < 4; ++r) acc[ct][r] = 0.f;

    const bf16* Arow = Abf + (size_t)n0 * 1024;
    const bf16* Xrow = Xt_in + (size_t)b * 65536;

    // register prefetch of tile kc=0
    bf16x8 pa[2], px[4];
#pragma unroll
    for (int i = 0; i < 2; ++i) {
        int g = i * 256 + t, row = g >> 4, c = g & 15;
        pa[i] = *(const bf16x8*)&Arow[(size_t)row * 1024 + c * 8];
    }
#pragma unroll
    for (int i = 0; i < 4; ++i) {
        int g = i * 256 + t, row = g >> 4, c = g & 15;
        px[i] = *(const bf16x8*)&Xrow[(size_t)row * 1024 + c * 8];
    }

    for (int kc = 0; kc < 1024; kc += 128) {
        __syncthreads();
#pragma unroll
        for (int i = 0; i < 2; ++i) {
            int g = i * 256 + t, row = g >> 4, c = g & 15;
            *(bf16x8*)&As[row * AS_STRIDE + c * 8] = pa[i];
        }
#pragma unroll
        for (int i = 0; i < 4; ++i) {
            int g = i * 256 + t, row = g >> 4, c = g & 15;
            *(bf16x8*)&Xs[row * AS_STRIDE + c * 8] = px[i];
        }
        __syncthreads();
        if (kc + 128 < 1024) {
#pragma unroll
            for (int i = 0; i < 2; ++i) {
                int g = i * 256 + t, row = g >> 4, c = g & 15;
                pa[i] = *(const bf16x8*)&Arow[(size_t)row * 1024 + kc + 128 + c * 8];
            }
#pragma unroll
            for (int i = 0; i < 4; ++i) {
                int g = i * 256 + t, row = g >> 4, c = g & 15;
                px[i] = *(const bf16x8*)&Xrow[(size_t)row * 1024 + kc + 128 + c * 8];
            }
        }
#pragma unroll
        for (int s = 0; s < 4; ++s) {
            bf16x8 a = *(const bf16x8*)&As[(rw * 16 + lm) * AS_STRIDE + s * 32 + q * 8];
#pragma unroll
            for (int ct = 0; ct < 2; ++ct) {
                bf16x8 bv = *(const bf16x8*)&Xs[(cth * 32 + ct * 16 + lm) * AS_STRIDE + s * 32 + q * 8];
                acc[ct] = __builtin_amdgcn_mfma_f32_16x16x32_bf16(a, bv, acc[ct], 0, 0, 0);
            }
        }
    }

    // epilogue: mu = relu(mu_1 + P + C3)
    float vals[2][4];
#pragma unroll
    for (int ct = 0; ct < 2; ++ct) {
        const int col = cth * 32 + ct * 16 + lm;
#pragma unroll
        for (int r = 0; r < 4; ++r) {
            const int n = n0 + rw * 16 + q * 4 + r;
            float v = mu_1[((size_t)b * Nc + n) * Dc + col] + acc[ct][r] + C3[n * 64 + col];
            vals[ct][r] = fmaxf(v, 0.f);
        }
    }

    __syncthreads();   // K-loop LDS reads done; safe to overwrite with epilogue buffers
    // stage epilogue weights from registers
    if (!FINAL) {
#pragma unroll
        for (int i = 0; i < 2; ++i) {
            int g = i * 256 + t, row = g >> 3, c = g & 7;
            *(bf16x8*)&WHi[row * MS_STRIDE + c * 8] = pw[i];
        }
    } else {
#pragma unroll
        for (int i = 0; i < 4; ++i) {
            int g = i * 1024 + t * 4;
            int h = g >> 6, d = g & 63;
            *(bf16x4*)&WHi[h * MS_STRIDE + d] = wrhi[i];
            *(bf16x4*)&WLo[h * MS_STRIDE + d] = wrlo[i];
        }
    }
    // write mu tile [n][d] (FINAL: hi/lo)
#pragma unroll
    for (int ct = 0; ct < 2; ++ct) {
        const int col = cth * 32 + ct * 16 + lm;
#pragma unroll
        for (int r = 0; r < 4; ++r) {
            const int row = rw * 16 + q * 4 + r;
            const float v = vals[ct][r];
            const bf16 hi = (bf16)v;
            muHi[row * MS_STRIDE + col] = hi;
            if (FINAL) muLo[row * MS_STRIDE + col] = (bf16)(v - (float)hi);
        }
    }
    if (FINAL) {
        // musum[b,col] += sum over this wave's 16 rows
#pragma unroll
        for (int ct = 0; ct < 2; ++ct) {
            float s = vals[ct][0] + vals[ct][1] + vals[ct][2] + vals[ct][3];
            s += __shfl_xor(s, 16);
            s += __shfl_xor(s, 32);
            if (q == 0) atomicAdd(&musum[b * 64 + cth * 32 + ct * 16 + lm], s);
        }
    }
    __syncthreads();

    f32x4 xacc[2];
#pragma unroll
    for (int ct = 0; ct < 2; ++ct)
#pragma unroll
        for (int r = 0; r < 4; ++r) xacc[ct][r] = 0.f;

    if (!FINAL) {
#pragma unroll
        for (int s = 0; s < 2; ++s) {
            bf16x8 a = *(const bf16x8*)&muHi[(rw * 16 + lm) * MS_STRIDE + s * 32 + q * 8];
#pragma unroll
            for (int ct = 0; ct < 2; ++ct) {
                bf16x8 bv = *(const bf16x8*)&WHi[(cth * 32 + ct * 16 + lm) * MS_STRIDE + s * 32 + q * 8];
                xacc[ct] = __builtin_amdgcn_mfma_f32_16x16x32_bf16(a, bv, xacc[ct], 0, 0, 0);
            }
        }
#pragma unroll
        for (int ct = 0; ct < 2; ++ct) {
            const int dd = cth * 32 + ct * 16 + lm;
            bf16x4 p;
#pragma unroll
            for (int r = 0; r < 4; ++r) p[r] = (bf16)xacc[ct][r];
            *(bf16x4*)&Xt_out[(size_t)b * 65536 + (size_t)dd * 1024 + n0 + rw * 16 + q * 4] = p;
        }
    } else {
        // split-precision head GEMM: P2 = muHi@WHi + muLo@WHi + muHi@WLo
#pragma unroll
        for (int s = 0; s < 2; ++s) {
            const int aoff = (rw * 16 + lm) * MS_STRIDE + s * 32 + q * 8;
            bf16x8 aHi = *(const bf16x8*)&muHi[aoff];
            bf16x8 aLo = *(const bf16x8*)&muLo[aoff];
#pragma unroll
            for (int ct = 0; ct < 2; ++ct) {
                const int boff = (cth * 32 + ct * 16 + lm) * MS_STRIDE + s * 32 + q * 8;
                bf16x8 bHi = *(const bf16x8*)&WHi[boff];
                bf16x8 bLo = *(const bf16x8*)&WLo[boff];
                xacc[ct] = __builtin_amdgcn_mfma_f32_16x16x32_bf16(aHi, bHi, xacc[ct], 0, 0, 0);
                xacc[ct] = __builtin_amdgcn_mfma_f32_16x16x32_bf16(aLo, bHi, xacc[ct], 0, 0, 0);
                xacc[ct] = __builtin_amdgcn_mfma_f32_16x16x32_bf16(aHi, bLo, xacc[ct], 0, 0, 0);
            }
        }
        // rowsum over this wave's 32 h's, reduce over lm, combine halves via LDS
        float rowsum[4] = {0.f, 0.f, 0.f, 0.f};
#pragma unroll
        for (int ct = 0; ct < 2; ++ct) {
            const int h = cth * 32 + ct * 16 + lm;
            const float c2 = c2base[b * 64 + h];
            const float wqh = Wq[h];
#pragma unroll
            for (int r = 0; r < 4; ++r)
                rowsum[r] += fmaxf(xacc[ct][r] + c2, 0.f) * wqh;
        }
#pragma unroll
        for (int r = 0; r < 4; ++r) {
            float v = rowsum[r];
            v += __shfl_xor(v, 1);
            v += __shfl_xor(v, 2);
            v += __shfl_xor(v, 4);
            v += __shfl_xor(v, 8);
            if (lm == 0) rpart[cth * 32 + rw * 16 + q * 4 + r] = v;
        }
        __syncthreads();
        if (t < 32)
            out[(size_t)b * (Nc + 1) + n0 + t] = rpart[t] + rpart[32 + t] + bq[0];
    }
}

// ---------------------------------------------------------------------------
// k_tail: mean row. grid B, block 64 (fp32)
// ---------------------------------------------------------------------------
__global__ void k_tail(const float* __restrict__ musum, const float* __restrict__ Wq1,
                       const float* __restrict__ bq1, const float* __restrict__ Wreg,
                       const float* __restrict__ c2base, const float* __restrict__ Wq,
                       const float* __restrict__ bq, float* __restrict__ out) {
    const int b = blockIdx.x, l = threadIdx.x;
    __shared__ float mean_s[64];
    __shared__ float mp[64];
    mean_s[l] = musum[b * 64 + l] * (1.f / Nc);
    __syncthreads();
    float a = bq1[l];
#pragma unroll
    for (int e = 0; e < 64; ++e) a = fmaf(mean_s[e], Wq1[l * 64 + e], a);
    mp[l] = fmaxf(a, 0.f);
    __syncthreads();
    float h = c2base[b * 64 + l];
#pragma unroll
    for (int d = 0; d < 64; ++d) h = fmaf(mp[d], Wreg[l * 128 + d], h);
    float v = fmaxf(h, 0.f) * Wq[l];
#pragma unroll
    for (int off = 32; off; off >>= 1) v += __shfl_down(v, off);
    if (l == 0) out[(size_t)b * (Nc + 1) + Nc] = v + bq[0];
}

// ---------------------------------------------------------------------------
extern "C" void kernel_launch(void* const* d_in, const int* in_sizes, int n_in,
                              void* d_out, int out_size, void* d_ws, size_t ws_size,
                              hipStream_t stream) {
    const float* xv     = (const float*)d_in[0];
    const float* option = (const float*)d_in[1];
    const float* adj    = (const float*)d_in[2];
    const float* mu1w   = (const float*)d_in[3];
    const float* W2     = (const float*)d_in[4];
    const float* b2     = (const float*)d_in[5];
    const float* W3     = (const float*)d_in[6];
    const float* b3     = (const float*)d_in[7];
    const float* W4     = (const float*)d_in[8];
    const float* b4     = (const float*)d_in[9];
    const float* Wq1    = (const float*)d_in[10];
    const float* bq1    = (const float*)d_in[11];
    const float* Wq2    = (const float*)d_in[12];
    const float* bq2    = (const float*)d_in[13];
    const float* Wreg   = (const float*)d_in[14];
    const float* breg   = (const float*)d_in[15];
    const float* Wq     = (const float*)d_in[16];
    const float* bq     = (const float*)d_in[17];
    float* out = (float*)d_out;

    float* ws = (float*)d_ws;
    const size_t MU = (size_t)Bc * Nc * Dc;          // 2,097,152
    float* mu_1     = ws;
    float* C3       = ws + MU;                       // 65536
    float* c2base   = C3 + 65536;                    // 2048
    float* musum    = c2base + 2048;                 // 2048
    bf16*  Abf      = (bf16*)(musum + 2048);         // 1M bf16
    bf16*  W2bf     = Abf + (size_t)Nc * Nc;         // 4096 bf16
    bf16*  Xt0      = W2bf + 4096;                   // B*D*N bf16
    bf16*  Xt1      = Xt0 + MU;

    k_pc<<<1025, 256, 0, stream>>>(adj, W4, b4, W3, b3, b2, W2, option, Wq2, bq2,
                                   Wreg, breg, Abf, C3, W2bf, c2base, musum);
    k_mu1<<<dim3(Nc / 64, Bc), 256, 0, stream>>>(xv, mu1w, W2bf, mu_1, Xt0);
    k_round<false><<<dim3(Bc, Nc / 32), 256, LDS_RND_NONF, stream>>>(
        Abf, Xt0, mu_1, C3, W2bf, Xt1,
        nullptr, nullptr, nullptr, nullptr, nullptr, nullptr);
    k_round<false><<<dim3(Bc, Nc / 32), 256, LDS_RND_NONF, stream>>>(
        Abf, Xt1, mu_1, C3, W2bf, Xt0,
        nullptr, nullptr, nullptr, nullptr, nullptr, nullptr);
    k_round<true><<<dim3(Bc, Nc / 32), 256, LDS_RND_FIN, stream>>>(
        Abf, Xt0, mu_1, C3, nullptr, nullptr,
        Wreg, c2base, Wq, bq, musum, out);
    k_tail<<<Bc, 64, 0, stream>>>(musum, Wq1, bq1, Wreg, c2base, Wq, bq, out);
}